// Round 8
// baseline (175.824 us; speedup 1.0000x reference)
//
#include <hip/hip_runtime.h>

// Problem constants: B=16, TQ=256, TK=256, QD=512, KD=512
// d_out = [ tanh_out: 16*256*512 f32 ; p: 16*256*256 f32 ]
// scores[b,q,k] = (sum_n w_n + b_att) - 2 * sum_n w_n / (1 + Ea[q,n]*Ek[k,n])
//   Ea = exp2(C2*aq), Ek = exp2(C2*keys), C2 = 2*log2(e)
// 4:1 rational combine (one rcp per 4 elems). n split in 4 quarters.
// K2 reads Ea/Ek DIRECTLY from global (L1/L2): broadcast-heavy access means
// bytes/instr equal the LDS path, but no barriers/staging and no LDS cap.

#define C2 2.88539008177792681f

typedef unsigned short u16;
typedef short s16x8 __attribute__((ext_vector_type(8)));
typedef float f32x4 __attribute__((ext_vector_type(4)));

__device__ __forceinline__ float fast_rcp(float x) { return __builtin_amdgcn_rcpf(x); }

__device__ __forceinline__ u16 f2bf(float f) {
  union { float f; unsigned u; } v; v.f = f;
  unsigned r = v.u + 0x7fffu + ((v.u >> 16) & 1u);
  return (u16)(r >> 16);
}
__device__ __forceinline__ unsigned packbf(float a, float b) {
  return (unsigned)f2bf(a) | ((unsigned)f2bf(b) << 16);
}

// ---------------------------------------------------------------------------
// Prep (fused): bf16-transpose Wq ([512][512]) and Wout ([1024][512]).
// grid (16, 48): by<16 -> Wq, else Wout.
// ---------------------------------------------------------------------------
__global__ __launch_bounds__(256) void transpose_w_bf16(
    const float* __restrict__ Wq, u16* __restrict__ Wqt,
    const float* __restrict__ Wout, u16* __restrict__ Woutt)
{
  __shared__ u16 tile[32][40];
  const int t = threadIdx.x;
  const int by = blockIdx.y;
  const float* W; u16* Wt; int K, k0;
  if (by < 16) { W = Wq;   Wt = Wqt;   K = 512;  k0 = by * 32; }
  else         { W = Wout; Wt = Woutt; K = 1024; k0 = (by - 16) * 32; }
  const int n0 = blockIdx.x * 32;
  const int r = t >> 3, c = (t & 7) * 4;
  float4 v = *(const float4*)&W[(size_t)(k0 + r) * 512 + n0 + c];
  tile[c + 0][r] = f2bf(v.x); tile[c + 1][r] = f2bf(v.y);
  tile[c + 2][r] = f2bf(v.z); tile[c + 3][r] = f2bf(v.w);
  __syncthreads();
  if (t < 128) {
    const int row = t >> 2, ch = (t & 3) * 8;
    unsigned p0 = (unsigned)tile[row][ch + 0] | ((unsigned)tile[row][ch + 1] << 16);
    unsigned p1 = (unsigned)tile[row][ch + 2] | ((unsigned)tile[row][ch + 3] << 16);
    unsigned p2 = (unsigned)tile[row][ch + 4] | ((unsigned)tile[row][ch + 5] << 16);
    unsigned p3 = (unsigned)tile[row][ch + 6] | ((unsigned)tile[row][ch + 7] << 16);
    *(int4*)&Wt[(size_t)(n0 + row) * K + k0 + ch] = make_int4(p0, p1, p2, p3);
  }
}

// ---------------------------------------------------------------------------
// K1/K4: bf16 MFMA GEMM. C[M][512] = act(A @ W + bias), A fp32 -> bf16 staged.
// Tile 64(M) x 64(N), BK=32, 4 waves (2x2), wave tile 32x32 (2x2 frags).
// ---------------------------------------------------------------------------
__global__ __launch_bounds__(256) void gemm_mfma_bf16(
    const float* __restrict__ A0, const float* __restrict__ A1, int kSplit,
    const u16* __restrict__ Bt, const float* __restrict__ bias,
    float* __restrict__ C, int K, int act)
{
  __shared__ u16 As[64 * 32];  // [row][k]
  __shared__ u16 Bs[64 * 32];  // [col][k]
  const int t = threadIdx.x;
  const int lane = t & 63, wid = t >> 6;
  const int wm = wid >> 1, wn = wid & 1;
  const int col0 = blockIdx.x * 64, row0 = blockIdx.y * 64;

  const int ar = t >> 2, ah = (t & 3) * 8;
  const int br = t >> 2, bc = (t & 3) * 8;
  const int fr = lane & 15, fg = (lane >> 4) * 8;

  f32x4 acc[2][2] = {};

  for (int k0 = 0; k0 < K; k0 += 32) {
    const float* Asrc; int kc;
    if (k0 < kSplit) { Asrc = A0; kc = k0; } else { Asrc = A1; kc = k0 - kSplit; }
    const float* ap = &Asrc[(size_t)(row0 + ar) * 512 + kc + ah];
    float4 av0 = *(const float4*)(ap + 0);
    float4 av1 = *(const float4*)(ap + 4);
    int4 bv = *(const int4*)&Bt[(size_t)(col0 + br) * K + k0 + bc];
    __syncthreads();
    {
      unsigned p0 = packbf(av0.x, av0.y), p1 = packbf(av0.z, av0.w);
      unsigned p2 = packbf(av1.x, av1.y), p3 = packbf(av1.z, av1.w);
      *(int4*)&As[ar * 32 + ah] = make_int4(p0, p1, p2, p3);
      *(int4*)&Bs[br * 32 + bc] = bv;
    }
    __syncthreads();

    s16x8 af[2], bf[2];
#pragma unroll
    for (int m = 0; m < 2; ++m)
      af[m] = *(const s16x8*)&As[(wm * 32 + m * 16 + fr) * 32 + fg];
#pragma unroll
    for (int n = 0; n < 2; ++n)
      bf[n] = *(const s16x8*)&Bs[(wn * 32 + n * 16 + fr) * 32 + fg];
#pragma unroll
    for (int m = 0; m < 2; ++m)
#pragma unroll
      for (int n = 0; n < 2; ++n)
        acc[m][n] = __builtin_amdgcn_mfma_f32_16x16x32_bf16(af[m], bf[n], acc[m][n], 0, 0, 0);
  }

  const int fq = lane >> 4;
#pragma unroll
  for (int n = 0; n < 2; ++n) {
    const int col = col0 + wn * 32 + n * 16 + fr;
    const float bv = bias[col];
#pragma unroll
    for (int m = 0; m < 2; ++m) {
#pragma unroll
      for (int i = 0; i < 4; ++i) {
        const int row = row0 + wm * 32 + m * 16 + fq * 4 + i;
        float v = acc[m][n][i] + bv;
        if (act == 1) {
          float e = __expf(2.0f * v);
          v = 1.0f - 2.0f * fast_rcp(e + 1.0f);
        } else if (act == 2) {
          v = exp2f(C2 * v);
        }
        C[(size_t)row * 512 + col] = v;
      }
    }
  }
}

// ---------------------------------------------------------------------------
// Kek: Ek = exp2(C2 * keys); block 0 reduces Cout = sum(w_att) + b_att.
// ---------------------------------------------------------------------------
__global__ __launch_bounds__(256) void ek_kernel(
    const float* __restrict__ keys, float* __restrict__ Ek,
    const float* __restrict__ w_att, const float* __restrict__ b_att,
    float* __restrict__ Cout)
{
  __shared__ float red[4];
  const int t = threadIdx.x;
  const size_t i4 = (size_t)blockIdx.x * 256 + t;
  float4 v = ((const float4*)keys)[i4];
  float4 o;
  o.x = exp2f(C2 * v.x); o.y = exp2f(C2 * v.y);
  o.z = exp2f(C2 * v.z); o.w = exp2f(C2 * v.w);
  ((float4*)Ek)[i4] = o;

  if (blockIdx.x == 0) {
    float wsum = w_att[t] + w_att[t + 256];
#pragma unroll
    for (int m = 32; m; m >>= 1) wsum += __shfl_xor(wsum, m);
    if ((t & 63) == 0) red[t >> 6] = wsum;
    __syncthreads();
    if (t == 0) Cout[0] = red[0] + red[1] + red[2] + red[3] + b_att[0];
  }
}

// ---------------------------------------------------------------------------
// K2: partial scores over an n-quarter (128). grid (8,4,64): 2048 blocks.
// b = z>>2, qt = z&3. Tile 64(q) x 32(k), 4x2 microtile, NO LDS, no barriers:
// Ea reads are 16-lane broadcast, Ek reads 16-row gather -> L1/L2 serves at
// LDS-equivalent bytes/instr. 8 blocks/CU -> 32-wave/CU occupancy cap.
// S layout: [4 qt][4096 q][256 k]; qt 0 adds Cv.
// ---------------------------------------------------------------------------
__global__ __launch_bounds__(256) void score_kernel(
    const float* __restrict__ Ea, const float* __restrict__ Ek,
    const float* __restrict__ w_att, const float* __restrict__ Cptr,
    float* __restrict__ S)
{
  const int z = blockIdx.z;
  const int b = z >> 2, qt = z & 3;
  const int q0 = blockIdx.y * 64, k0 = blockIdx.x * 32;
  const int t = threadIdx.x;
  const int qi = t >> 4, ki = t & 15;

  const float* eap = Ea + (size_t)(b * 256 + q0 + qi) * 512 + qt * 128;
  const float* ekp = Ek + (size_t)(b * 256 + k0 + ki) * 512 + qt * 128;
  const float* wp  = w_att + qt * 128;

  float acc[4][2] = {};

#pragma unroll 2
  for (int j = 0; j < 128; j += 4) {
    float4 av[4], kv[2];
#pragma unroll
    for (int m = 0; m < 4; ++m) av[m] = *(const float4*)&eap[m * 16 * 512 + j];
#pragma unroll
    for (int n = 0; n < 2; ++n) kv[n] = *(const float4*)&ekp[n * 16 * 512 + j];
    float4 wv = *(const float4*)&wp[j];  // wave-uniform -> scalar loads
#pragma unroll
    for (int m = 0; m < 4; ++m) {
#pragma unroll
      for (int n = 0; n < 2; ++n) {
        float q1 = fmaf(av[m].x, kv[n].x, 1.0f);
        float q2 = fmaf(av[m].y, kv[n].y, 1.0f);
        float q3 = fmaf(av[m].z, kv[n].z, 1.0f);
        float q4 = fmaf(av[m].w, kv[n].w, 1.0f);
        float N12 = fmaf(wv.x, q2, wv.y * q1);
        float D12 = q1 * q2;
        float N34 = fmaf(wv.z, q4, wv.w * q3);
        float D34 = q3 * q4;
        float Nt = fmaf(N12, D34, N34 * D12);
        float Dt = D12 * D34;
        acc[m][n] = fmaf(Nt, fast_rcp(Dt), acc[m][n]);
      }
    }
  }

  const float Cv = (qt == 0) ? Cptr[0] : 0.0f;
  float* sc = S + (size_t)qt * 1048576;
#pragma unroll
  for (int m = 0; m < 4; ++m) {
    const size_t qr = (size_t)(b * 256 + q0 + qi + m * 16);
#pragma unroll
    for (int n = 0; n < 2; ++n)
      sc[qr * 256 + k0 + ki + n * 16] = fmaf(-2.f, acc[m][n], Cv);
  }
}

// ---------------------------------------------------------------------------
// K3: softmax over k of sum of 4 partials (writes p) + ctx = p @ keys[b]
// ---------------------------------------------------------------------------
__global__ __launch_bounds__(256) void softmax_ctx_kernel(
    const float* __restrict__ S, const float* __restrict__ keys,
    float* __restrict__ p_out, float* __restrict__ ctx)
{
  __shared__ float p_s[16][260];
  __shared__ float k_s[16 * 512];

  const int b = blockIdx.y, q0 = blockIdx.x * 16;
  const int t = threadIdx.x;
  const int wv = t >> 6, lane = t & 63;

#pragma unroll
  for (int i = 0; i < 4; ++i) {
    const int r = wv * 4 + i;
    const size_t off = (size_t)(b * 256 + q0 + r) * 256 + lane * 4;
    float4 sa = *(const float4*)&S[off];
    float4 sb = *(const float4*)&S[off + 1048576];
    float4 sc = *(const float4*)&S[off + 2097152];
    float4 sd = *(const float4*)&S[off + 3145728];
    float4 s4 = {(sa.x + sb.x) + (sc.x + sd.x), (sa.y + sb.y) + (sc.y + sd.y),
                 (sa.z + sb.z) + (sc.z + sd.z), (sa.w + sb.w) + (sc.w + sd.w)};
    float m = fmaxf(fmaxf(s4.x, s4.y), fmaxf(s4.z, s4.w));
#pragma unroll
    for (int msk = 32; msk; msk >>= 1) m = fmaxf(m, __shfl_xor(m, msk));
    float e0 = __expf(s4.x - m);
    float e1 = __expf(s4.y - m);
    float e2 = __expf(s4.z - m);
    float e3 = __expf(s4.w - m);
    float ssum = (e0 + e1) + (e2 + e3);
#pragma unroll
    for (int msk = 32; msk; msk >>= 1) ssum += __shfl_xor(ssum, msk);
    float rs = 1.0f / ssum;
    float4 p4 = {e0 * rs, e1 * rs, e2 * rs, e3 * rs};
    *(float4*)&p_s[r][lane * 4] = p4;
    *(float4*)&p_out[off] = p4;
  }

  const int qg = t >> 6;
  const int ng = t & 63;
  float acc[4][8] = {};
  for (int kc = 0; kc < 256; kc += 16) {
    __syncthreads();
    const float* kbase = keys + (size_t)(b * 256 + kc) * 512;
#pragma unroll
    for (int u = 0; u < 8; ++u)
      *(float4*)&k_s[u * 1024 + t * 4] = *(const float4*)&kbase[u * 1024 + t * 4];
    __syncthreads();
#pragma unroll 4
    for (int kk = 0; kk < 16; ++kk) {
      float p0 = p_s[qg * 4 + 0][kc + kk];
      float p1 = p_s[qg * 4 + 1][kc + kk];
      float p2 = p_s[qg * 4 + 2][kc + kk];
      float p3 = p_s[qg * 4 + 3][kc + kk];
#pragma unroll
      for (int j = 0; j < 8; ++j) {
        float kv = k_s[kk * 512 + ng + j * 64];
        acc[0][j] = fmaf(p0, kv, acc[0][j]);
        acc[1][j] = fmaf(p1, kv, acc[1][j]);
        acc[2][j] = fmaf(p2, kv, acc[2][j]);
        acc[3][j] = fmaf(p3, kv, acc[3][j]);
      }
    }
  }

  __syncthreads();
#pragma unroll
  for (int i = 0; i < 4; ++i)
#pragma unroll
    for (int j = 0; j < 8; ++j)
      k_s[(qg * 4 + i) * 512 + ng + j * 64] = acc[i][j];
  __syncthreads();
  float* cb = ctx + (size_t)(b * 256 + q0) * 512;
#pragma unroll
  for (int u = 0; u < 8; ++u)
    *(float4*)&cb[u * 1024 + t * 4] = *(const float4*)&k_s[u * 1024 + t * 4];
}

// ---------------------------------------------------------------------------
extern "C" void kernel_launch(void* const* d_in, const int* in_sizes, int n_in,
                              void* d_out, int out_size, void* d_ws, size_t ws_size,
                              hipStream_t stream) {
  const float* query = (const float*)d_in[0];
  const float* keys  = (const float*)d_in[1];
  const float* Wq    = (const float*)d_in[2];
  const float* bq    = (const float*)d_in[3];
  const float* w_att = (const float*)d_in[4];
  const float* b_att = (const float*)d_in[5];
  const float* Wout  = (const float*)d_in[6];
  const float* bout  = (const float*)d_in[7];

  float* out_tanh = (float*)d_out;                  // [4096][512]
  float* out_p    = out_tanh + (size_t)4096 * 512;  // [4096][256]

  float* ws = (float*)d_ws;
  float* Ea     = ws;                    // [4096][512] f32
  float* Ek     = ws + 2097152;          // [4096][512] f32
  float* S      = ws + 4194304;          // [4][4096][256] f32 partial scores
  float* Cptr   = ws + 8388608;          // [1] (+pad)
  u16*   Wqt    = (u16*)(ws + 8388624);  // [512][512] bf16
  u16*   Woutt  = Wqt + 262144;          // [512][1024] bf16
  float* ctx    = Ea;                    // alias: Ea dead when K3 writes ctx

  transpose_w_bf16<<<dim3(16, 48), 256, 0, stream>>>(Wq, Wqt, Wout, Woutt);

  ek_kernel<<<2048, 256, 0, stream>>>(keys, Ek, w_att, b_att, Cptr);

  // K1: Ea = exp2(C2 * (query @ Wq + bq))   [MFMA bf16, 64x64 tile]
  gemm_mfma_bf16<<<dim3(8, 64), 256, 0, stream>>>(
      query, query, 512, Wqt, bq, Ea, 512, 2);

  // K2: partial scores (4 n-quarters), 64x32 tiles, NO LDS, 2048 blocks
  score_kernel<<<dim3(8, 4, 64), 256, 0, stream>>>(
      Ea, Ek, w_att, Cptr, S);

  // K3: softmax of sum(S[0..3]) (writes p) + context
  softmax_ctx_kernel<<<dim3(16, 16), 256, 0, stream>>>(
      S, keys, out_p, ctx);

  // K4: out = tanh(concat(query, ctx) @ Wout + bout)   [MFMA bf16]
  gemm_mfma_bf16<<<dim3(8, 64), 256, 0, stream>>>(
      query, ctx, 512, Woutt, bout, out_tanh, 1024, 1);
}

// Round 9
// 141.737 us; speedup vs baseline: 1.2405x; 1.2405x over previous
//
#include <hip/hip_runtime.h>

// Problem constants: B=16, TQ=256, TK=256, QD=512, KD=512
// d_out = [ tanh_out: 16*256*512 f32 ; p: 16*256*256 f32 ]
// scores[b,q,k] = (sum_n w_n + b_att) - 2 * sum_n w_n / (1 + Ea[q,n]*Ek[k,n])
//   Ea = exp2(C2*aq), Ek = exp2(C2*keys), C2 = 2*log2(e)
// 4:1 rational combine (one rcp per 4 elems). n split in 4 quarters.
// R8 lesson: direct-global score reads starve on VMEM (broadcast/gather ->
// 16 cachelines/instr). LDS staging + register prefetch instead.

#define C2 2.88539008177792681f

typedef unsigned short u16;
typedef short s16x8 __attribute__((ext_vector_type(8)));
typedef float f32x4 __attribute__((ext_vector_type(4)));

__device__ __forceinline__ float fast_rcp(float x) { return __builtin_amdgcn_rcpf(x); }

__device__ __forceinline__ u16 f2bf(float f) {
  union { float f; unsigned u; } v; v.f = f;
  unsigned r = v.u + 0x7fffu + ((v.u >> 16) & 1u);
  return (u16)(r >> 16);
}
__device__ __forceinline__ unsigned packbf(float a, float b) {
  return (unsigned)f2bf(a) | ((unsigned)f2bf(b) << 16);
}

// ---------------------------------------------------------------------------
// Prep (fused): bf16-transpose Wq ([512][512]) and Wout ([1024][512]).
// ---------------------------------------------------------------------------
__global__ __launch_bounds__(256) void transpose_w_bf16(
    const float* __restrict__ Wq, u16* __restrict__ Wqt,
    const float* __restrict__ Wout, u16* __restrict__ Woutt)
{
  __shared__ u16 tile[32][40];
  const int t = threadIdx.x;
  const int by = blockIdx.y;
  const float* W; u16* Wt; int K, k0;
  if (by < 16) { W = Wq;   Wt = Wqt;   K = 512;  k0 = by * 32; }
  else         { W = Wout; Wt = Woutt; K = 1024; k0 = (by - 16) * 32; }
  const int n0 = blockIdx.x * 32;
  const int r = t >> 3, c = (t & 7) * 4;
  float4 v = *(const float4*)&W[(size_t)(k0 + r) * 512 + n0 + c];
  tile[c + 0][r] = f2bf(v.x); tile[c + 1][r] = f2bf(v.y);
  tile[c + 2][r] = f2bf(v.z); tile[c + 3][r] = f2bf(v.w);
  __syncthreads();
  if (t < 128) {
    const int row = t >> 2, ch = (t & 3) * 8;
    unsigned p0 = (unsigned)tile[row][ch + 0] | ((unsigned)tile[row][ch + 1] << 16);
    unsigned p1 = (unsigned)tile[row][ch + 2] | ((unsigned)tile[row][ch + 3] << 16);
    unsigned p2 = (unsigned)tile[row][ch + 4] | ((unsigned)tile[row][ch + 5] << 16);
    unsigned p3 = (unsigned)tile[row][ch + 6] | ((unsigned)tile[row][ch + 7] << 16);
    *(int4*)&Wt[(size_t)(n0 + row) * K + k0 + ch] = make_int4(p0, p1, p2, p3);
  }
}

// ---------------------------------------------------------------------------
// K1/K4: bf16 MFMA GEMM. C[M][512] = act(A @ W + bias), A fp32 -> bf16 staged.
// Tile 64(M) x 64(N), BK=32, 4 waves (2x2), wave tile 32x32 (2x2 frags).
// ---------------------------------------------------------------------------
__global__ __launch_bounds__(256) void gemm_mfma_bf16(
    const float* __restrict__ A0, const float* __restrict__ A1, int kSplit,
    const u16* __restrict__ Bt, const float* __restrict__ bias,
    float* __restrict__ C, int K, int act)
{
  __shared__ u16 As[64 * 32];  // [row][k]
  __shared__ u16 Bs[64 * 32];  // [col][k]
  const int t = threadIdx.x;
  const int lane = t & 63, wid = t >> 6;
  const int wm = wid >> 1, wn = wid & 1;
  const int col0 = blockIdx.x * 64, row0 = blockIdx.y * 64;

  const int ar = t >> 2, ah = (t & 3) * 8;
  const int br = t >> 2, bc = (t & 3) * 8;
  const int fr = lane & 15, fg = (lane >> 4) * 8;

  f32x4 acc[2][2] = {};

  for (int k0 = 0; k0 < K; k0 += 32) {
    const float* Asrc; int kc;
    if (k0 < kSplit) { Asrc = A0; kc = k0; } else { Asrc = A1; kc = k0 - kSplit; }
    const float* ap = &Asrc[(size_t)(row0 + ar) * 512 + kc + ah];
    float4 av0 = *(const float4*)(ap + 0);
    float4 av1 = *(const float4*)(ap + 4);
    int4 bv = *(const int4*)&Bt[(size_t)(col0 + br) * K + k0 + bc];
    __syncthreads();
    {
      unsigned p0 = packbf(av0.x, av0.y), p1 = packbf(av0.z, av0.w);
      unsigned p2 = packbf(av1.x, av1.y), p3 = packbf(av1.z, av1.w);
      *(int4*)&As[ar * 32 + ah] = make_int4(p0, p1, p2, p3);
      *(int4*)&Bs[br * 32 + bc] = bv;
    }
    __syncthreads();

    s16x8 af[2], bf[2];
#pragma unroll
    for (int m = 0; m < 2; ++m)
      af[m] = *(const s16x8*)&As[(wm * 32 + m * 16 + fr) * 32 + fg];
#pragma unroll
    for (int n = 0; n < 2; ++n)
      bf[n] = *(const s16x8*)&Bs[(wn * 32 + n * 16 + fr) * 32 + fg];
#pragma unroll
    for (int m = 0; m < 2; ++m)
#pragma unroll
      for (int n = 0; n < 2; ++n)
        acc[m][n] = __builtin_amdgcn_mfma_f32_16x16x32_bf16(af[m], bf[n], acc[m][n], 0, 0, 0);
  }

  const int fq = lane >> 4;
#pragma unroll
  for (int n = 0; n < 2; ++n) {
    const int col = col0 + wn * 32 + n * 16 + fr;
    const float bv = bias[col];
#pragma unroll
    for (int m = 0; m < 2; ++m) {
#pragma unroll
      for (int i = 0; i < 4; ++i) {
        const int row = row0 + wm * 32 + m * 16 + fq * 4 + i;
        float v = acc[m][n][i] + bv;
        if (act == 1) {
          float e = __expf(2.0f * v);
          v = 1.0f - 2.0f * fast_rcp(e + 1.0f);
        } else if (act == 2) {
          v = exp2f(C2 * v);
        }
        C[(size_t)row * 512 + col] = v;
      }
    }
  }
}

// ---------------------------------------------------------------------------
// Kek: Ek = exp2(C2 * keys); block 0 reduces Cout = sum(w_att) + b_att.
// ---------------------------------------------------------------------------
__global__ __launch_bounds__(256) void ek_kernel(
    const float* __restrict__ keys, float* __restrict__ Ek,
    const float* __restrict__ w_att, const float* __restrict__ b_att,
    float* __restrict__ Cout)
{
  __shared__ float red[4];
  const int t = threadIdx.x;
  const size_t i4 = (size_t)blockIdx.x * 256 + t;
  float4 v = ((const float4*)keys)[i4];
  float4 o;
  o.x = exp2f(C2 * v.x); o.y = exp2f(C2 * v.y);
  o.z = exp2f(C2 * v.z); o.w = exp2f(C2 * v.w);
  ((float4*)Ek)[i4] = o;

  if (blockIdx.x == 0) {
    float wsum = w_att[t] + w_att[t + 256];
#pragma unroll
    for (int m = 32; m; m >>= 1) wsum += __shfl_xor(wsum, m);
    if ((t & 63) == 0) red[t >> 6] = wsum;
    __syncthreads();
    if (t == 0) Cout[0] = red[0] + red[1] + red[2] + red[3] + b_att[0];
  }
}

// ---------------------------------------------------------------------------
// K2: partial scores over an n-QUARTER (128 values). grid (4,4,64):
// b = z>>2, qt = z&3. 64x64 (q,k) tile, 4x4 microtile, 4:1-combined rcp.
// LDS staged (R8: direct-global starves VMEM) with REGISTER PREFETCH of
// chunk c+1 issued after the barrier, hidden under the 64-j compute.
// S layout: [4 qt][4096 q][256 k]; qt 0 adds Cv.
// ---------------------------------------------------------------------------
__global__ __launch_bounds__(256) void score_kernel(
    const float* __restrict__ Ea, const float* __restrict__ Ek,
    const float* __restrict__ w_att, const float* __restrict__ Cptr,
    float* __restrict__ S)
{
  __shared__ float ea_s[64][68];
  __shared__ float ek_s[64][68];
  __shared__ float w_s[128];

  const int z = blockIdx.z;
  const int b = z >> 2, qt = z & 3;
  const int q0 = blockIdx.y * 64, k0 = blockIdx.x * 64;
  const int t = threadIdx.x;
  if (t < 128) w_s[t] = w_att[qt * 128 + t];

  const int qi = t >> 4, ki = t & 15;       // microtile origin
  const int lr = t >> 2, lc = (t & 3) * 16; // staging: row, 16-elem chunk
  const float* eap = Ea + (size_t)(b * 256 + q0) * 512 + qt * 128;
  const float* ekp = Ek + (size_t)(b * 256 + k0) * 512 + qt * 128;

  float acc[4][4] = {};

  int gb = lr * 512 + lc;
  float4 A0 = *(const float4*)&eap[gb + 0];
  float4 A1 = *(const float4*)&eap[gb + 4];
  float4 A2 = *(const float4*)&eap[gb + 8];
  float4 A3 = *(const float4*)&eap[gb + 12];
  float4 K0 = *(const float4*)&ekp[gb + 0];
  float4 K1 = *(const float4*)&ekp[gb + 4];
  float4 K2 = *(const float4*)&ekp[gb + 8];
  float4 K3 = *(const float4*)&ekp[gb + 12];

  for (int c = 0; c < 2; ++c) {
    __syncthreads();  // prev chunk consumed (covers w_s init at c=0)
    *(float4*)&ea_s[lr][lc + 0]  = A0;
    *(float4*)&ea_s[lr][lc + 4]  = A1;
    *(float4*)&ea_s[lr][lc + 8]  = A2;
    *(float4*)&ea_s[lr][lc + 12] = A3;
    *(float4*)&ek_s[lr][lc + 0]  = K0;
    *(float4*)&ek_s[lr][lc + 4]  = K1;
    *(float4*)&ek_s[lr][lc + 8]  = K2;
    *(float4*)&ek_s[lr][lc + 12] = K3;
    __syncthreads();

    if (c == 0) {  // prefetch next chunk; latency hides under compute below
      gb += 64;
      A0 = *(const float4*)&eap[gb + 0];
      A1 = *(const float4*)&eap[gb + 4];
      A2 = *(const float4*)&eap[gb + 8];
      A3 = *(const float4*)&eap[gb + 12];
      K0 = *(const float4*)&ekp[gb + 0];
      K1 = *(const float4*)&ekp[gb + 4];
      K2 = *(const float4*)&ekp[gb + 8];
      K3 = *(const float4*)&ekp[gb + 12];
    }

    for (int j = 0; j < 64; j += 4) {
      float4 av[4], kv[4];
#pragma unroll
      for (int m = 0; m < 4; ++m) av[m] = *(const float4*)&ea_s[qi + m * 16][j];
#pragma unroll
      for (int n = 0; n < 4; ++n) kv[n] = *(const float4*)&ek_s[ki + n * 16][j];
      float4 wv = *(const float4*)&w_s[c * 64 + j];
#pragma unroll
      for (int m = 0; m < 4; ++m) {
#pragma unroll
        for (int n = 0; n < 4; ++n) {
          float q1 = fmaf(av[m].x, kv[n].x, 1.0f);
          float q2 = fmaf(av[m].y, kv[n].y, 1.0f);
          float q3 = fmaf(av[m].z, kv[n].z, 1.0f);
          float q4 = fmaf(av[m].w, kv[n].w, 1.0f);
          float N12 = fmaf(wv.x, q2, wv.y * q1);
          float D12 = q1 * q2;
          float N34 = fmaf(wv.z, q4, wv.w * q3);
          float D34 = q3 * q4;
          float Nt = fmaf(N12, D34, N34 * D12);
          float Dt = D12 * D34;
          acc[m][n] = fmaf(Nt, fast_rcp(Dt), acc[m][n]);
        }
      }
    }
  }

  const float Cv = (qt == 0) ? Cptr[0] : 0.0f;
  float* sc = S + (size_t)qt * 1048576;
#pragma unroll
  for (int m = 0; m < 4; ++m) {
    const size_t qr = (size_t)(b * 256 + q0 + qi + m * 16);
#pragma unroll
    for (int n = 0; n < 4; ++n)
      sc[qr * 256 + k0 + ki + n * 16] = fmaf(-2.f, acc[m][n], Cv);
  }
}

// ---------------------------------------------------------------------------
// K3: softmax over k of sum of 4 partials + ctx = p @ keys[b].
// n split in 2 halves across blocks: grid (2, 16, 16) = 512 blocks (2/CU).
// Softmax duplicated per half (cheap); only half 0 writes p_out.
// ---------------------------------------------------------------------------
__global__ __launch_bounds__(256) void softmax_ctx_kernel(
    const float* __restrict__ S, const float* __restrict__ keys,
    float* __restrict__ p_out, float* __restrict__ ctx)
{
  __shared__ float p_s[16][260];
  __shared__ float k_s[16 * 256];

  const int nh = blockIdx.x;            // n-half: cols nh*256 .. +255
  const int q0 = blockIdx.y * 16;
  const int b = blockIdx.z;
  const int t = threadIdx.x;
  const int wv = t >> 6, lane = t & 63;

#pragma unroll
  for (int i = 0; i < 4; ++i) {
    const int r = wv * 4 + i;
    const size_t off = (size_t)(b * 256 + q0 + r) * 256 + lane * 4;
    float4 sa = *(const float4*)&S[off];
    float4 sb = *(const float4*)&S[off + 1048576];
    float4 sc = *(const float4*)&S[off + 2097152];
    float4 sd = *(const float4*)&S[off + 3145728];
    float4 s4 = {(sa.x + sb.x) + (sc.x + sd.x), (sa.y + sb.y) + (sc.y + sd.y),
                 (sa.z + sb.z) + (sc.z + sd.z), (sa.w + sb.w) + (sc.w + sd.w)};
    float m = fmaxf(fmaxf(s4.x, s4.y), fmaxf(s4.z, s4.w));
#pragma unroll
    for (int msk = 32; msk; msk >>= 1) m = fmaxf(m, __shfl_xor(m, msk));
    float e0 = __expf(s4.x - m);
    float e1 = __expf(s4.y - m);
    float e2 = __expf(s4.z - m);
    float e3 = __expf(s4.w - m);
    float ssum = (e0 + e1) + (e2 + e3);
#pragma unroll
    for (int msk = 32; msk; msk >>= 1) ssum += __shfl_xor(ssum, msk);
    float rs = 1.0f / ssum;
    float4 p4 = {e0 * rs, e1 * rs, e2 * rs, e3 * rs};
    *(float4*)&p_s[r][lane * 4] = p4;
    if (nh == 0) *(float4*)&p_out[off] = p4;
  }

  const int qg = t >> 6;                 // wave id: q rows qg*4..+3
  const int ng = t & 63;                 // n cols: ng + j*64 within half
  const int srow = t >> 6, scol = (t & 63) * 4;  // staging coords
  float acc[4][4] = {};
  for (int kc = 0; kc < 256; kc += 16) {
    __syncthreads();  // p_s ready (first iter) / prev k_s consumed
    const float* kbase = keys + (size_t)(b * 256 + kc) * 512 + nh * 256;
#pragma unroll
    for (int u = 0; u < 4; ++u) {
      const int row = u * 4 + srow;
      *(float4*)&k_s[row * 256 + scol] = *(const float4*)&kbase[(size_t)row * 512 + scol];
    }
    __syncthreads();
#pragma unroll 4
    for (int kk = 0; kk < 16; ++kk) {
      float p0 = p_s[qg * 4 + 0][kc + kk];
      float p1 = p_s[qg * 4 + 1][kc + kk];
      float p2 = p_s[qg * 4 + 2][kc + kk];
      float p3 = p_s[qg * 4 + 3][kc + kk];
#pragma unroll
      for (int j = 0; j < 4; ++j) {
        float kv = k_s[kk * 256 + ng + j * 64];
        acc[0][j] = fmaf(p0, kv, acc[0][j]);
        acc[1][j] = fmaf(p1, kv, acc[1][j]);
        acc[2][j] = fmaf(p2, kv, acc[2][j]);
        acc[3][j] = fmaf(p3, kv, acc[3][j]);
      }
    }
  }

  // restage ctx tile [16][256] for coalesced writes
  __syncthreads();
#pragma unroll
  for (int i = 0; i < 4; ++i)
#pragma unroll
    for (int j = 0; j < 4; ++j)
      k_s[(qg * 4 + i) * 256 + ng + j * 64] = acc[i][j];
  __syncthreads();
  float* cb = ctx + (size_t)(b * 256 + q0) * 512 + nh * 256;
#pragma unroll
  for (int u = 0; u < 4; ++u) {
    const int row = u * 4 + srow;
    *(float4*)&cb[(size_t)row * 512 + scol] = *(const float4*)&k_s[row * 256 + scol];
  }
}

// ---------------------------------------------------------------------------
extern "C" void kernel_launch(void* const* d_in, const int* in_sizes, int n_in,
                              void* d_out, int out_size, void* d_ws, size_t ws_size,
                              hipStream_t stream) {
  const float* query = (const float*)d_in[0];
  const float* keys  = (const float*)d_in[1];
  const float* Wq    = (const float*)d_in[2];
  const float* bq    = (const float*)d_in[3];
  const float* w_att = (const float*)d_in[4];
  const float* b_att = (const float*)d_in[5];
  const float* Wout  = (const float*)d_in[6];
  const float* bout  = (const float*)d_in[7];

  float* out_tanh = (float*)d_out;                  // [4096][512]
  float* out_p    = out_tanh + (size_t)4096 * 512;  // [4096][256]

  float* ws = (float*)d_ws;
  float* Ea     = ws;                    // [4096][512] f32
  float* Ek     = ws + 2097152;          // [4096][512] f32
  float* S      = ws + 4194304;          // [4][4096][256] f32 partial scores
  float* Cptr   = ws + 8388608;          // [1] (+pad)
  u16*   Wqt    = (u16*)(ws + 8388624);  // [512][512] bf16
  u16*   Woutt  = Wqt + 262144;          // [512][1024] bf16
  float* ctx    = Ea;                    // alias: Ea dead when K3 writes ctx

  transpose_w_bf16<<<dim3(16, 48), 256, 0, stream>>>(Wq, Wqt, Wout, Woutt);

  ek_kernel<<<2048, 256, 0, stream>>>(keys, Ek, w_att, b_att, Cptr);

  // K1: Ea = exp2(C2 * (query @ Wq + bq))   [MFMA bf16, 64x64 tile]
  gemm_mfma_bf16<<<dim3(8, 64), 256, 0, stream>>>(
      query, query, 512, Wqt, bq, Ea, 512, 2);

  // K2: partial scores (4 n-quarters), 64x64 tiles, LDS + reg prefetch
  score_kernel<<<dim3(4, 4, 64), 256, 0, stream>>>(
      Ea, Ek, w_att, Cptr, S);

  // K3: softmax of sum(S) (writes p) + context, n-halved (512 blocks)
  softmax_ctx_kernel<<<dim3(2, 16, 16), 256, 0, stream>>>(
      S, keys, out_p, ctx);

  // K4: out = tanh(concat(query, ctx) @ Wout + bout)   [MFMA bf16]
  gemm_mfma_bf16<<<dim3(8, 64), 256, 0, stream>>>(
      query, ctx, 512, Woutt, bout, out_tanh, 1024, 1);
}

// Round 10
// 134.848 us; speedup vs baseline: 1.3039x; 1.0511x over previous
//
#include <hip/hip_runtime.h>

// Problem constants: B=16, TQ=256, TK=256, QD=512, KD=512
// d_out = [ tanh_out: 16*256*512 f32 ; p: 16*256*256 f32 ]
// scores[b,q,k] = (sum_n w_n + b_att) - 2 * sum_n w_n / (1 + Ea[q,n]*Ek[k,n])
//   Ea = exp2(C2*aq), Ek = exp2(C2*keys), C2 = 2*log2(e)
// 4:1 rational combine (one rcp per 4 elems). n split in 4 quarters.
// R10: 64q x 32k tile, 32-n chunks -> 14.3KB LDS, 8 blocks/CU, 2048 blocks.

#define C2 2.88539008177792681f

typedef unsigned short u16;
typedef short s16x8 __attribute__((ext_vector_type(8)));
typedef float f32x4 __attribute__((ext_vector_type(4)));

__device__ __forceinline__ float fast_rcp(float x) { return __builtin_amdgcn_rcpf(x); }

__device__ __forceinline__ u16 f2bf(float f) {
  union { float f; unsigned u; } v; v.f = f;
  unsigned r = v.u + 0x7fffu + ((v.u >> 16) & 1u);
  return (u16)(r >> 16);
}
__device__ __forceinline__ unsigned packbf(float a, float b) {
  return (unsigned)f2bf(a) | ((unsigned)f2bf(b) << 16);
}

// ---------------------------------------------------------------------------
// Prep (fused): bf16-transpose Wq ([512][512]) and Wout ([1024][512]).
// ---------------------------------------------------------------------------
__global__ __launch_bounds__(256) void transpose_w_bf16(
    const float* __restrict__ Wq, u16* __restrict__ Wqt,
    const float* __restrict__ Wout, u16* __restrict__ Woutt)
{
  __shared__ u16 tile[32][40];
  const int t = threadIdx.x;
  const int by = blockIdx.y;
  const float* W; u16* Wt; int K, k0;
  if (by < 16) { W = Wq;   Wt = Wqt;   K = 512;  k0 = by * 32; }
  else         { W = Wout; Wt = Woutt; K = 1024; k0 = (by - 16) * 32; }
  const int n0 = blockIdx.x * 32;
  const int r = t >> 3, c = (t & 7) * 4;
  float4 v = *(const float4*)&W[(size_t)(k0 + r) * 512 + n0 + c];
  tile[c + 0][r] = f2bf(v.x); tile[c + 1][r] = f2bf(v.y);
  tile[c + 2][r] = f2bf(v.z); tile[c + 3][r] = f2bf(v.w);
  __syncthreads();
  if (t < 128) {
    const int row = t >> 2, ch = (t & 3) * 8;
    unsigned p0 = (unsigned)tile[row][ch + 0] | ((unsigned)tile[row][ch + 1] << 16);
    unsigned p1 = (unsigned)tile[row][ch + 2] | ((unsigned)tile[row][ch + 3] << 16);
    unsigned p2 = (unsigned)tile[row][ch + 4] | ((unsigned)tile[row][ch + 5] << 16);
    unsigned p3 = (unsigned)tile[row][ch + 6] | ((unsigned)tile[row][ch + 7] << 16);
    *(int4*)&Wt[(size_t)(n0 + row) * K + k0 + ch] = make_int4(p0, p1, p2, p3);
  }
}

// ---------------------------------------------------------------------------
// K1/K4: bf16 MFMA GEMM. C[M][512] = act(A @ W + bias), A fp32 -> bf16 staged.
// Tile 64(M) x 64(N), BK=32, 4 waves (2x2), wave tile 32x32 (2x2 frags).
// ---------------------------------------------------------------------------
__global__ __launch_bounds__(256) void gemm_mfma_bf16(
    const float* __restrict__ A0, const float* __restrict__ A1, int kSplit,
    const u16* __restrict__ Bt, const float* __restrict__ bias,
    float* __restrict__ C, int K, int act)
{
  __shared__ u16 As[64 * 32];  // [row][k]
  __shared__ u16 Bs[64 * 32];  // [col][k]
  const int t = threadIdx.x;
  const int lane = t & 63, wid = t >> 6;
  const int wm = wid >> 1, wn = wid & 1;
  const int col0 = blockIdx.x * 64, row0 = blockIdx.y * 64;

  const int ar = t >> 2, ah = (t & 3) * 8;
  const int br = t >> 2, bc = (t & 3) * 8;
  const int fr = lane & 15, fg = (lane >> 4) * 8;

  f32x4 acc[2][2] = {};

  for (int k0 = 0; k0 < K; k0 += 32) {
    const float* Asrc; int kc;
    if (k0 < kSplit) { Asrc = A0; kc = k0; } else { Asrc = A1; kc = k0 - kSplit; }
    const float* ap = &Asrc[(size_t)(row0 + ar) * 512 + kc + ah];
    float4 av0 = *(const float4*)(ap + 0);
    float4 av1 = *(const float4*)(ap + 4);
    int4 bv = *(const int4*)&Bt[(size_t)(col0 + br) * K + k0 + bc];
    __syncthreads();
    {
      unsigned p0 = packbf(av0.x, av0.y), p1 = packbf(av0.z, av0.w);
      unsigned p2 = packbf(av1.x, av1.y), p3 = packbf(av1.z, av1.w);
      *(int4*)&As[ar * 32 + ah] = make_int4(p0, p1, p2, p3);
      *(int4*)&Bs[br * 32 + bc] = bv;
    }
    __syncthreads();

    s16x8 af[2], bf[2];
#pragma unroll
    for (int m = 0; m < 2; ++m)
      af[m] = *(const s16x8*)&As[(wm * 32 + m * 16 + fr) * 32 + fg];
#pragma unroll
    for (int n = 0; n < 2; ++n)
      bf[n] = *(const s16x8*)&Bs[(wn * 32 + n * 16 + fr) * 32 + fg];
#pragma unroll
    for (int m = 0; m < 2; ++m)
#pragma unroll
      for (int n = 0; n < 2; ++n)
        acc[m][n] = __builtin_amdgcn_mfma_f32_16x16x32_bf16(af[m], bf[n], acc[m][n], 0, 0, 0);
  }

  const int fq = lane >> 4;
#pragma unroll
  for (int n = 0; n < 2; ++n) {
    const int col = col0 + wn * 32 + n * 16 + fr;
    const float bv = bias[col];
#pragma unroll
    for (int m = 0; m < 2; ++m) {
#pragma unroll
      for (int i = 0; i < 4; ++i) {
        const int row = row0 + wm * 32 + m * 16 + fq * 4 + i;
        float v = acc[m][n][i] + bv;
        if (act == 1) {
          float e = __expf(2.0f * v);
          v = 1.0f - 2.0f * fast_rcp(e + 1.0f);
        } else if (act == 2) {
          v = exp2f(C2 * v);
        }
        C[(size_t)row * 512 + col] = v;
      }
    }
  }
}

// ---------------------------------------------------------------------------
// Kek: Ek = exp2(C2 * keys); block 0 reduces Cout = sum(w_att) + b_att.
// ---------------------------------------------------------------------------
__global__ __launch_bounds__(256) void ek_kernel(
    const float* __restrict__ keys, float* __restrict__ Ek,
    const float* __restrict__ w_att, const float* __restrict__ b_att,
    float* __restrict__ Cout)
{
  __shared__ float red[4];
  const int t = threadIdx.x;
  const size_t i4 = (size_t)blockIdx.x * 256 + t;
  float4 v = ((const float4*)keys)[i4];
  float4 o;
  o.x = exp2f(C2 * v.x); o.y = exp2f(C2 * v.y);
  o.z = exp2f(C2 * v.z); o.w = exp2f(C2 * v.w);
  ((float4*)Ek)[i4] = o;

  if (blockIdx.x == 0) {
    float wsum = w_att[t] + w_att[t + 256];
#pragma unroll
    for (int m = 32; m; m >>= 1) wsum += __shfl_xor(wsum, m);
    if ((t & 63) == 0) red[t >> 6] = wsum;
    __syncthreads();
    if (t == 0) Cout[0] = red[0] + red[1] + red[2] + red[3] + b_att[0];
  }
}

// ---------------------------------------------------------------------------
// K2: partial scores over an n-QUARTER (128). grid (8,4,64) = 2048 blocks:
// b = z>>2, qt = z&3, k0 = bx*32, q0 = by*64. Tile 64q x 32k, 4x2 microtile.
// 32-n LDS chunks (14.3KB total) -> 8 blocks/CU; reg prefetch of next chunk.
// S layout: [4 qt][4096 q][256 k]; qt 0 adds Cv.
// ---------------------------------------------------------------------------
__global__ __launch_bounds__(256) void score_kernel(
    const float* __restrict__ Ea, const float* __restrict__ Ek,
    const float* __restrict__ w_att, const float* __restrict__ Cptr,
    float* __restrict__ S)
{
  __shared__ float ea_s[64][36];
  __shared__ float ek_s[32][36];
  __shared__ float w_s[128];

  const int z = blockIdx.z;
  const int b = z >> 2, qt = z & 3;
  const int q0 = blockIdx.y * 64, k0 = blockIdx.x * 32;
  const int t = threadIdx.x;
  if (t < 128) w_s[t] = w_att[qt * 128 + t];

  const int qi = t >> 4, ki = t & 15;        // microtile: q rows qi+m*16, k cols ki+n*16
  const int alr = t >> 2, alc = (t & 3) * 8; // ea staging: row 0..63, 8-elem chunk
  const int klr = t >> 3, klc = (t & 7) * 4; // ek staging: row 0..31, 4-elem chunk
  const float* eap = Ea + (size_t)(b * 256 + q0) * 512 + qt * 128;
  const float* ekp = Ek + (size_t)(b * 256 + k0) * 512 + qt * 128;

  float acc[4][2] = {};

  // prefetch chunk 0
  float4 pA0 = *(const float4*)&eap[alr * 512 + alc + 0];
  float4 pA1 = *(const float4*)&eap[alr * 512 + alc + 4];
  float4 pK0 = *(const float4*)&ekp[klr * 512 + klc];

  for (int c = 0; c < 4; ++c) {
    __syncthreads();  // prev chunk consumed (covers w_s init at c=0)
    *(float4*)&ea_s[alr][alc + 0] = pA0;
    *(float4*)&ea_s[alr][alc + 4] = pA1;
    *(float4*)&ek_s[klr][klc]     = pK0;
    __syncthreads();

    if (c < 3) {  // prefetch next chunk; latency hides under compute below
      const int nb = (c + 1) * 32;
      pA0 = *(const float4*)&eap[alr * 512 + nb + alc + 0];
      pA1 = *(const float4*)&eap[alr * 512 + nb + alc + 4];
      pK0 = *(const float4*)&ekp[klr * 512 + nb + klc];
    }

#pragma unroll
    for (int j = 0; j < 32; j += 4) {
      float4 av[4], kv[2];
#pragma unroll
      for (int m = 0; m < 4; ++m) av[m] = *(const float4*)&ea_s[qi + m * 16][j];
#pragma unroll
      for (int n = 0; n < 2; ++n) kv[n] = *(const float4*)&ek_s[ki + n * 16][j];
      float4 wv = *(const float4*)&w_s[c * 32 + j];
#pragma unroll
      for (int m = 0; m < 4; ++m) {
#pragma unroll
        for (int n = 0; n < 2; ++n) {
          float q1 = fmaf(av[m].x, kv[n].x, 1.0f);
          float q2 = fmaf(av[m].y, kv[n].y, 1.0f);
          float q3 = fmaf(av[m].z, kv[n].z, 1.0f);
          float q4 = fmaf(av[m].w, kv[n].w, 1.0f);
          float N12 = fmaf(wv.x, q2, wv.y * q1);
          float D12 = q1 * q2;
          float N34 = fmaf(wv.z, q4, wv.w * q3);
          float D34 = q3 * q4;
          float Nt = fmaf(N12, D34, N34 * D12);
          float Dt = D12 * D34;
          acc[m][n] = fmaf(Nt, fast_rcp(Dt), acc[m][n]);
        }
      }
    }
  }

  const float Cv = (qt == 0) ? Cptr[0] : 0.0f;
  float* sc = S + (size_t)qt * 1048576;
#pragma unroll
  for (int m = 0; m < 4; ++m) {
    const size_t qr = (size_t)(b * 256 + q0 + qi + m * 16);
#pragma unroll
    for (int n = 0; n < 2; ++n)
      sc[qr * 256 + k0 + ki + n * 16] = fmaf(-2.f, acc[m][n], Cv);
  }
}

// ---------------------------------------------------------------------------
// K3: softmax over k of sum of 4 partials + ctx = p @ keys[b].
// n split in 2 halves across blocks: grid (2, 16, 16) = 512 blocks.
// Softmax duplicated per half; only half 0 writes p_out.
// ---------------------------------------------------------------------------
__global__ __launch_bounds__(256) void softmax_ctx_kernel(
    const float* __restrict__ S, const float* __restrict__ keys,
    float* __restrict__ p_out, float* __restrict__ ctx)
{
  __shared__ float p_s[16][260];
  __shared__ float k_s[16 * 256];

  const int nh = blockIdx.x;
  const int q0 = blockIdx.y * 16;
  const int b = blockIdx.z;
  const int t = threadIdx.x;
  const int wv = t >> 6, lane = t & 63;

#pragma unroll
  for (int i = 0; i < 4; ++i) {
    const int r = wv * 4 + i;
    const size_t off = (size_t)(b * 256 + q0 + r) * 256 + lane * 4;
    float4 sa = *(const float4*)&S[off];
    float4 sb = *(const float4*)&S[off + 1048576];
    float4 sc = *(const float4*)&S[off + 2097152];
    float4 sd = *(const float4*)&S[off + 3145728];
    float4 s4 = {(sa.x + sb.x) + (sc.x + sd.x), (sa.y + sb.y) + (sc.y + sd.y),
                 (sa.z + sb.z) + (sc.z + sd.z), (sa.w + sb.w) + (sc.w + sd.w)};
    float m = fmaxf(fmaxf(s4.x, s4.y), fmaxf(s4.z, s4.w));
#pragma unroll
    for (int msk = 32; msk; msk >>= 1) m = fmaxf(m, __shfl_xor(m, msk));
    float e0 = __expf(s4.x - m);
    float e1 = __expf(s4.y - m);
    float e2 = __expf(s4.z - m);
    float e3 = __expf(s4.w - m);
    float ssum = (e0 + e1) + (e2 + e3);
#pragma unroll
    for (int msk = 32; msk; msk >>= 1) ssum += __shfl_xor(ssum, msk);
    float rs = 1.0f / ssum;
    float4 p4 = {e0 * rs, e1 * rs, e2 * rs, e3 * rs};
    *(float4*)&p_s[r][lane * 4] = p4;
    if (nh == 0) *(float4*)&p_out[off] = p4;
  }

  const int qg = t >> 6;
  const int ng = t & 63;
  const int srow = t >> 6, scol = (t & 63) * 4;
  float acc[4][4] = {};
  for (int kc = 0; kc < 256; kc += 16) {
    __syncthreads();
    const float* kbase = keys + (size_t)(b * 256 + kc) * 512 + nh * 256;
#pragma unroll
    for (int u = 0; u < 4; ++u) {
      const int row = u * 4 + srow;
      *(float4*)&k_s[row * 256 + scol] = *(const float4*)&kbase[(size_t)row * 512 + scol];
    }
    __syncthreads();
#pragma unroll 4
    for (int kk = 0; kk < 16; ++kk) {
      float p0 = p_s[qg * 4 + 0][kc + kk];
      float p1 = p_s[qg * 4 + 1][kc + kk];
      float p2 = p_s[qg * 4 + 2][kc + kk];
      float p3 = p_s[qg * 4 + 3][kc + kk];
#pragma unroll
      for (int j = 0; j < 4; ++j) {
        float kv = k_s[kk * 256 + ng + j * 64];
        acc[0][j] = fmaf(p0, kv, acc[0][j]);
        acc[1][j] = fmaf(p1, kv, acc[1][j]);
        acc[2][j] = fmaf(p2, kv, acc[2][j]);
        acc[3][j] = fmaf(p3, kv, acc[3][j]);
      }
    }
  }

  __syncthreads();
#pragma unroll
  for (int i = 0; i < 4; ++i)
#pragma unroll
    for (int j = 0; j < 4; ++j)
      k_s[(qg * 4 + i) * 256 + ng + j * 64] = acc[i][j];
  __syncthreads();
  float* cb = ctx + (size_t)(b * 256 + q0) * 512 + nh * 256;
#pragma unroll
  for (int u = 0; u < 4; ++u) {
    const int row = u * 4 + srow;
    *(float4*)&cb[(size_t)row * 512 + scol] = *(const float4*)&k_s[row * 256 + scol];
  }
}

// ---------------------------------------------------------------------------
extern "C" void kernel_launch(void* const* d_in, const int* in_sizes, int n_in,
                              void* d_out, int out_size, void* d_ws, size_t ws_size,
                              hipStream_t stream) {
  const float* query = (const float*)d_in[0];
  const float* keys  = (const float*)d_in[1];
  const float* Wq    = (const float*)d_in[2];
  const float* bq    = (const float*)d_in[3];
  const float* w_att = (const float*)d_in[4];
  const float* b_att = (const float*)d_in[5];
  const float* Wout  = (const float*)d_in[6];
  const float* bout  = (const float*)d_in[7];

  float* out_tanh = (float*)d_out;                  // [4096][512]
  float* out_p    = out_tanh + (size_t)4096 * 512;  // [4096][256]

  float* ws = (float*)d_ws;
  float* Ea     = ws;                    // [4096][512] f32
  float* Ek     = ws + 2097152;          // [4096][512] f32
  float* S      = ws + 4194304;          // [4][4096][256] f32 partial scores
  float* Cptr   = ws + 8388608;          // [1] (+pad)
  u16*   Wqt    = (u16*)(ws + 8388624);  // [512][512] bf16
  u16*   Woutt  = Wqt + 262144;          // [512][1024] bf16
  float* ctx    = Ea;                    // alias: Ea dead when K3 writes ctx

  transpose_w_bf16<<<dim3(16, 48), 256, 0, stream>>>(Wq, Wqt, Wout, Woutt);

  ek_kernel<<<2048, 256, 0, stream>>>(keys, Ek, w_att, b_att, Cptr);

  // K1: Ea = exp2(C2 * (query @ Wq + bq))   [MFMA bf16, 64x64 tile]
  gemm_mfma_bf16<<<dim3(8, 64), 256, 0, stream>>>(
      query, query, 512, Wqt, bq, Ea, 512, 2);

  // K2: partial scores (4 n-quarters), 64x32 tiles, 32-n chunks, 2048 blocks
  score_kernel<<<dim3(8, 4, 64), 256, 0, stream>>>(
      Ea, Ek, w_att, Cptr, S);

  // K3: softmax of sum(S) (writes p) + context, n-halved (512 blocks)
  softmax_ctx_kernel<<<dim3(2, 16, 16), 256, 0, stream>>>(
      S, keys, out_p, ctx);

  // K4: out = tanh(concat(query, ctx) @ Wout + bout)   [MFMA bf16]
  gemm_mfma_bf16<<<dim3(8, 64), 256, 0, stream>>>(
      query, ctx, 512, Woutt, bout, out_tanh, 1024, 1);
}

// Round 11
// 124.649 us; speedup vs baseline: 1.4106x; 1.0818x over previous
//
#include <hip/hip_runtime.h>

// Problem constants: B=16, TQ=256, TK=256, QD=512, KD=512
// d_out = [ tanh_out: 16*256*512 f32 ; p: 16*256*256 f32 ]
// scores[b,q,k] = (sum_n w_n + b_att) - 2 * sum_n w_n / (1 + Ea[q,n]*Ek[k,n])
//   Ea = exp2(C2*aq), Ek = exp2(C2*keys), C2 = 2*log2(e)
// 4:1 rational combine (one rcp per 4 elems). n split in 4 quarters.
// R11: score = R7 config (best measured). GEMMs: padded-LDS (40-elem rows,
// kills 8-way b128 read conflict of 64B rows), pure-bf16 A path (qbf/ctxbf
// precomputed -> staging is int4 copies, no in-loop packing).

#define C2 2.88539008177792681f

typedef unsigned short u16;
typedef short s16x8 __attribute__((ext_vector_type(8)));
typedef float f32x4 __attribute__((ext_vector_type(4)));

__device__ __forceinline__ float fast_rcp(float x) { return __builtin_amdgcn_rcpf(x); }

__device__ __forceinline__ u16 f2bf(float f) {
  union { float f; unsigned u; } v; v.f = f;
  unsigned r = v.u + 0x7fffu + ((v.u >> 16) & 1u);
  return (u16)(r >> 16);
}
__device__ __forceinline__ unsigned packbf(float a, float b) {
  return (unsigned)f2bf(a) | ((unsigned)f2bf(b) << 16);
}

// ---------------------------------------------------------------------------
// Prep: blocks [0,2048): Ek = exp2(C2*keys) (block 0 also reduces
// Cout = sum(w)+b_att). Blocks [2048,3072): qbf = bf16(query).
// ---------------------------------------------------------------------------
__global__ __launch_bounds__(256) void prep_kernel(
    const float* __restrict__ keys, float* __restrict__ Ek,
    const float* __restrict__ query, u16* __restrict__ qbf,
    const float* __restrict__ w_att, const float* __restrict__ b_att,
    float* __restrict__ Cout)
{
  __shared__ float red[4];
  const int t = threadIdx.x;
  const int bx = blockIdx.x;
  if (bx < 2048) {
    const size_t i4 = (size_t)bx * 256 + t;
    float4 v = ((const float4*)keys)[i4];
    float4 o;
    o.x = exp2f(C2 * v.x); o.y = exp2f(C2 * v.y);
    o.z = exp2f(C2 * v.z); o.w = exp2f(C2 * v.w);
    ((float4*)Ek)[i4] = o;
    if (bx == 0) {
      float wsum = w_att[t] + w_att[t + 256];
#pragma unroll
      for (int m = 32; m; m >>= 1) wsum += __shfl_xor(wsum, m);
      if ((t & 63) == 0) red[t >> 6] = wsum;
      __syncthreads();
      if (t == 0) Cout[0] = red[0] + red[1] + red[2] + red[3] + b_att[0];
    }
  } else {
    const size_t i8 = ((size_t)(bx - 2048) * 256 + t) * 8;
    float4 a = *(const float4*)&query[i8];
    float4 b = *(const float4*)&query[i8 + 4];
    unsigned p0 = packbf(a.x, a.y), p1 = packbf(a.z, a.w);
    unsigned p2 = packbf(b.x, b.y), p3 = packbf(b.z, b.w);
    *(int4*)&qbf[i8] = make_int4(p0, p1, p2, p3);
  }
}

// ---------------------------------------------------------------------------
// Prep (fused): bf16-transpose Wq ([512][512]) and Wout ([1024][512]).
// ---------------------------------------------------------------------------
__global__ __launch_bounds__(256) void transpose_w_bf16(
    const float* __restrict__ Wq, u16* __restrict__ Wqt,
    const float* __restrict__ Wout, u16* __restrict__ Woutt)
{
  __shared__ u16 tile[32][40];
  const int t = threadIdx.x;
  const int by = blockIdx.y;
  const float* W; u16* Wt; int K, k0;
  if (by < 16) { W = Wq;   Wt = Wqt;   K = 512;  k0 = by * 32; }
  else         { W = Wout; Wt = Woutt; K = 1024; k0 = (by - 16) * 32; }
  const int n0 = blockIdx.x * 32;
  const int r = t >> 3, c = (t & 7) * 4;
  float4 v = *(const float4*)&W[(size_t)(k0 + r) * 512 + n0 + c];
  tile[c + 0][r] = f2bf(v.x); tile[c + 1][r] = f2bf(v.y);
  tile[c + 2][r] = f2bf(v.z); tile[c + 3][r] = f2bf(v.w);
  __syncthreads();
  if (t < 128) {
    const int row = t >> 2, ch = (t & 3) * 8;
    unsigned p0 = (unsigned)tile[row][ch + 0] | ((unsigned)tile[row][ch + 1] << 16);
    unsigned p1 = (unsigned)tile[row][ch + 2] | ((unsigned)tile[row][ch + 3] << 16);
    unsigned p2 = (unsigned)tile[row][ch + 4] | ((unsigned)tile[row][ch + 5] << 16);
    unsigned p3 = (unsigned)tile[row][ch + 6] | ((unsigned)tile[row][ch + 7] << 16);
    *(int4*)&Wt[(size_t)(n0 + row) * K + k0 + ch] = make_int4(p0, p1, p2, p3);
  }
}

// ---------------------------------------------------------------------------
// K1/K4: bf16 MFMA GEMM, all-bf16 operands. C[M][512] = act(A @ W + bias).
// A: bf16 [M][512] split A0/A1 at kSplit (concat). Bt: bf16 [512 n][K k].
// Tile 64x64, BK=32, 4 waves (2x2), wave tile 32x32 (2x2 frags).
// LDS rows padded to 40 elems (80B): b128 frag reads <=2-way banks (was 8-way
// at 64B rows). Staging = pure int4 copies (A pre-converted to bf16).
// ---------------------------------------------------------------------------
__global__ __launch_bounds__(256) void gemm_mfma_bf16(
    const u16* __restrict__ A0, const u16* __restrict__ A1, int kSplit,
    const u16* __restrict__ Bt, const float* __restrict__ bias,
    float* __restrict__ C, int K, int act)
{
  __shared__ u16 As[64 * 40];  // [row][k], padded
  __shared__ u16 Bs[64 * 40];  // [col][k], padded
  const int t = threadIdx.x;
  const int lane = t & 63, wid = t >> 6;
  const int wm = wid >> 1, wn = wid & 1;
  const int col0 = blockIdx.x * 64, row0 = blockIdx.y * 64;

  const int ar = t >> 2, ah = (t & 3) * 8;  // row 0..63, 8-elem chunk of 32k
  const int fr = lane & 15, fg = (lane >> 4) * 8;

  f32x4 acc[2][2] = {};

  for (int k0 = 0; k0 < K; k0 += 32) {
    const u16* Asrc; int kc;
    if (k0 < kSplit) { Asrc = A0; kc = k0; } else { Asrc = A1; kc = k0 - kSplit; }
    int4 aval = *(const int4*)&Asrc[(size_t)(row0 + ar) * 512 + kc + ah];
    int4 bval = *(const int4*)&Bt[(size_t)(col0 + ar) * K + k0 + ah];
    __syncthreads();
    *(int4*)&As[ar * 40 + ah] = aval;
    *(int4*)&Bs[ar * 40 + ah] = bval;
    __syncthreads();

    s16x8 af[2], bf[2];
#pragma unroll
    for (int m = 0; m < 2; ++m)
      af[m] = *(const s16x8*)&As[(wm * 32 + m * 16 + fr) * 40 + fg];
#pragma unroll
    for (int n = 0; n < 2; ++n)
      bf[n] = *(const s16x8*)&Bs[(wn * 32 + n * 16 + fr) * 40 + fg];
#pragma unroll
    for (int m = 0; m < 2; ++m)
#pragma unroll
      for (int n = 0; n < 2; ++n)
        acc[m][n] = __builtin_amdgcn_mfma_f32_16x16x32_bf16(af[m], bf[n], acc[m][n], 0, 0, 0);
  }

  const int fq = lane >> 4;
#pragma unroll
  for (int n = 0; n < 2; ++n) {
    const int col = col0 + wn * 32 + n * 16 + fr;
    const float bv = bias[col];
#pragma unroll
    for (int m = 0; m < 2; ++m) {
#pragma unroll
      for (int i = 0; i < 4; ++i) {
        const int row = row0 + wm * 32 + m * 16 + fq * 4 + i;
        float v = acc[m][n][i] + bv;
        if (act == 1) {
          float e = __expf(2.0f * v);
          v = 1.0f - 2.0f * fast_rcp(e + 1.0f);
        } else if (act == 2) {
          v = exp2f(C2 * v);
        }
        C[(size_t)row * 512 + col] = v;
      }
    }
  }
}

// ---------------------------------------------------------------------------
// K2: partial scores over an n-QUARTER (128 values). grid (4,4,64):
// b = z>>2, qt = z&3. 64x64 (q,k) tile, 4x4 microtile, 4:1-combined rcp.
// EXACT R7 config (best measured: 55.9us). S: [4 qt][4096 q][256 k].
// ---------------------------------------------------------------------------
__global__ __launch_bounds__(256) void score_kernel(
    const float* __restrict__ Ea, const float* __restrict__ Ek,
    const float* __restrict__ w_att, const float* __restrict__ Cptr,
    float* __restrict__ S)
{
  __shared__ float ea_s[64][68];
  __shared__ float ek_s[64][68];
  __shared__ float w_s[128];

  const int z = blockIdx.z;
  const int b = z >> 2, qt = z & 3;
  const int q0 = blockIdx.y * 64, k0 = blockIdx.x * 64;
  const int t = threadIdx.x;
  if (t < 128) w_s[t] = w_att[qt * 128 + t];

  const int qi = t >> 4, ki = t & 15;
  const int lr = t >> 2, lc = (t & 3) * 16;
  const float* eap = Ea + (size_t)(b * 256 + q0) * 512 + qt * 128;
  const float* ekp = Ek + (size_t)(b * 256 + k0) * 512 + qt * 128;

  float acc[4][4] = {};

  for (int c = 0; c < 2; ++c) {
    const int gb = lr * 512 + c * 64 + lc;
    float4 A0 = *(const float4*)&eap[gb + 0];
    float4 A1 = *(const float4*)&eap[gb + 4];
    float4 A2 = *(const float4*)&eap[gb + 8];
    float4 A3 = *(const float4*)&eap[gb + 12];
    float4 K0 = *(const float4*)&ekp[gb + 0];
    float4 K1 = *(const float4*)&ekp[gb + 4];
    float4 K2 = *(const float4*)&ekp[gb + 8];
    float4 K3 = *(const float4*)&ekp[gb + 12];
    __syncthreads();  // prev chunk consumed (covers w_s init at c=0)
    *(float4*)&ea_s[lr][lc + 0]  = A0;
    *(float4*)&ea_s[lr][lc + 4]  = A1;
    *(float4*)&ea_s[lr][lc + 8]  = A2;
    *(float4*)&ea_s[lr][lc + 12] = A3;
    *(float4*)&ek_s[lr][lc + 0]  = K0;
    *(float4*)&ek_s[lr][lc + 4]  = K1;
    *(float4*)&ek_s[lr][lc + 8]  = K2;
    *(float4*)&ek_s[lr][lc + 12] = K3;
    __syncthreads();

    for (int j = 0; j < 64; j += 4) {
      float4 av[4], kv[4];
#pragma unroll
      for (int m = 0; m < 4; ++m) av[m] = *(const float4*)&ea_s[qi + m * 16][j];
#pragma unroll
      for (int n = 0; n < 4; ++n) kv[n] = *(const float4*)&ek_s[ki + n * 16][j];
      float4 wv = *(const float4*)&w_s[c * 64 + j];
#pragma unroll
      for (int m = 0; m < 4; ++m) {
#pragma unroll
        for (int n = 0; n < 4; ++n) {
          float q1 = fmaf(av[m].x, kv[n].x, 1.0f);
          float q2 = fmaf(av[m].y, kv[n].y, 1.0f);
          float q3 = fmaf(av[m].z, kv[n].z, 1.0f);
          float q4 = fmaf(av[m].w, kv[n].w, 1.0f);
          float N12 = fmaf(wv.x, q2, wv.y * q1);
          float D12 = q1 * q2;
          float N34 = fmaf(wv.z, q4, wv.w * q3);
          float D34 = q3 * q4;
          float Nt = fmaf(N12, D34, N34 * D12);
          float Dt = D12 * D34;
          acc[m][n] = fmaf(Nt, fast_rcp(Dt), acc[m][n]);
        }
      }
    }
  }

  const float Cv = (qt == 0) ? Cptr[0] : 0.0f;
  float* sc = S + (size_t)qt * 1048576;
#pragma unroll
  for (int m = 0; m < 4; ++m) {
    const size_t qr = (size_t)(b * 256 + q0 + qi + m * 16);
#pragma unroll
    for (int n = 0; n < 4; ++n)
      sc[qr * 256 + k0 + ki + n * 16] = fmaf(-2.f, acc[m][n], Cv);
  }
}

// ---------------------------------------------------------------------------
// K3: softmax over k of sum of 4 partials + ctx(bf16) = p @ keys[b].
// n split in 2 halves: grid (2, 16, 16). Only half 0 writes p_out.
// ctx written directly as bf16 (consumed only by K4's bf16 A path).
// ---------------------------------------------------------------------------
__global__ __launch_bounds__(256) void softmax_ctx_kernel(
    const float* __restrict__ S, const float* __restrict__ keys,
    float* __restrict__ p_out, u16* __restrict__ ctxbf)
{
  __shared__ float p_s[16][260];
  __shared__ float k_s[16 * 256];

  const int nh = blockIdx.x;
  const int q0 = blockIdx.y * 16;
  const int b = blockIdx.z;
  const int t = threadIdx.x;
  const int wv = t >> 6, lane = t & 63;

#pragma unroll
  for (int i = 0; i < 4; ++i) {
    const int r = wv * 4 + i;
    const size_t off = (size_t)(b * 256 + q0 + r) * 256 + lane * 4;
    float4 sa = *(const float4*)&S[off];
    float4 sb = *(const float4*)&S[off + 1048576];
    float4 sc = *(const float4*)&S[off + 2097152];
    float4 sd = *(const float4*)&S[off + 3145728];
    float4 s4 = {(sa.x + sb.x) + (sc.x + sd.x), (sa.y + sb.y) + (sc.y + sd.y),
                 (sa.z + sb.z) + (sc.z + sd.z), (sa.w + sb.w) + (sc.w + sd.w)};
    float m = fmaxf(fmaxf(s4.x, s4.y), fmaxf(s4.z, s4.w));
#pragma unroll
    for (int msk = 32; msk; msk >>= 1) m = fmaxf(m, __shfl_xor(m, msk));
    float e0 = __expf(s4.x - m);
    float e1 = __expf(s4.y - m);
    float e2 = __expf(s4.z - m);
    float e3 = __expf(s4.w - m);
    float ssum = (e0 + e1) + (e2 + e3);
#pragma unroll
    for (int msk = 32; msk; msk >>= 1) ssum += __shfl_xor(ssum, msk);
    float rs = 1.0f / ssum;
    float4 p4 = {e0 * rs, e1 * rs, e2 * rs, e3 * rs};
    *(float4*)&p_s[r][lane * 4] = p4;
    if (nh == 0) *(float4*)&p_out[off] = p4;
  }

  const int qg = t >> 6;
  const int ng = t & 63;
  const int srow = t >> 6, scol = (t & 63) * 4;
  float acc[4][4] = {};
  for (int kc = 0; kc < 256; kc += 16) {
    __syncthreads();
    const float* kbase = keys + (size_t)(b * 256 + kc) * 512 + nh * 256;
#pragma unroll
    for (int u = 0; u < 4; ++u) {
      const int row = u * 4 + srow;
      *(float4*)&k_s[row * 256 + scol] = *(const float4*)&kbase[(size_t)row * 512 + scol];
    }
    __syncthreads();
#pragma unroll 4
    for (int kk = 0; kk < 16; ++kk) {
      float p0 = p_s[qg * 4 + 0][kc + kk];
      float p1 = p_s[qg * 4 + 1][kc + kk];
      float p2 = p_s[qg * 4 + 2][kc + kk];
      float p3 = p_s[qg * 4 + 3][kc + kk];
#pragma unroll
      for (int j = 0; j < 4; ++j) {
        float kv = k_s[kk * 256 + ng + j * 64];
        acc[0][j] = fmaf(p0, kv, acc[0][j]);
        acc[1][j] = fmaf(p1, kv, acc[1][j]);
        acc[2][j] = fmaf(p2, kv, acc[2][j]);
        acc[3][j] = fmaf(p3, kv, acc[3][j]);
      }
    }
  }

  // direct bf16 stores: per (i,j) the wave writes 64 consecutive u16 = 128B
#pragma unroll
  for (int i = 0; i < 4; ++i) {
    const size_t rb = (size_t)(b * 256 + q0 + qg * 4 + i) * 512 + nh * 256;
#pragma unroll
    for (int j = 0; j < 4; ++j)
      ctxbf[rb + ng + j * 64] = f2bf(acc[i][j]);
  }
}

// ---------------------------------------------------------------------------
extern "C" void kernel_launch(void* const* d_in, const int* in_sizes, int n_in,
                              void* d_out, int out_size, void* d_ws, size_t ws_size,
                              hipStream_t stream) {
  const float* query = (const float*)d_in[0];
  const float* keys  = (const float*)d_in[1];
  const float* Wq    = (const float*)d_in[2];
  const float* bq    = (const float*)d_in[3];
  const float* w_att = (const float*)d_in[4];
  const float* b_att = (const float*)d_in[5];
  const float* Wout  = (const float*)d_in[6];
  const float* bout  = (const float*)d_in[7];

  float* out_tanh = (float*)d_out;                  // [4096][512]
  float* out_p    = out_tanh + (size_t)4096 * 512;  // [4096][256]

  float* ws = (float*)d_ws;
  float* Ea     = ws;                    // [4096][512] f32 (dead after K2)
  float* Ek     = ws + 2097152;          // [4096][512] f32 (dead after K2)
  float* S      = ws + 4194304;          // [4][4096][256] f32 partial scores
  float* Cptr   = ws + 8388608;          // [1] (+pad to 16)
  u16*   Wqt    = (u16*)(ws + 8388624);  // [512][512] bf16
  u16*   Woutt  = Wqt + 262144;          // [512][1024] bf16
  u16*   qbf    = Woutt + 524288;        // [4096][512] bf16
  u16*   ctxbf  = (u16*)Ea;              // [4096][512] bf16, aliases dead Ea

  // Prep: Ek + Cptr + qbf
  prep_kernel<<<3072, 256, 0, stream>>>(keys, Ek, query, qbf, w_att, b_att, Cptr);

  // Prep: transposed bf16 weights
  transpose_w_bf16<<<dim3(16, 48), 256, 0, stream>>>(Wq, Wqt, Wout, Woutt);

  // K1: Ea = exp2(C2 * (qbf @ Wq + bq))   [MFMA bf16, padded LDS]
  gemm_mfma_bf16<<<dim3(8, 64), 256, 0, stream>>>(
      qbf, qbf, 512, Wqt, bq, Ea, 512, 2);

  // K2: partial scores (4 n-quarters), R7 config
  score_kernel<<<dim3(4, 4, 64), 256, 0, stream>>>(
      Ea, Ek, w_att, Cptr, S);

  // K3: softmax of sum(S) (writes p) + context as bf16
  softmax_ctx_kernel<<<dim3(2, 16, 16), 256, 0, stream>>>(
      S, keys, out_p, ctxbf);

  // K4: out = tanh(concat(qbf, ctxbf) @ Wout + bout)   [MFMA bf16]
  gemm_mfma_bf16<<<dim3(8, 64), 256, 0, stream>>>(
      qbf, ctxbf, 512, Woutt, bout, out_tanh, 1024, 1);
}

// Round 12
// 102.587 us; speedup vs baseline: 1.7139x; 1.2151x over previous
//
#include <hip/hip_runtime.h>

// Problem constants: B=16, TQ=256, TK=256, QD=512, KD=512
// d_out = [ tanh_out: 16*256*512 f32 ; p: 16*256*256 f32 ]
// scores[b,q,k] = (sum_n w_n + b_att) - 2 * sum_n w_n / (1 + Ea[q,n]*Ek[k,n])
//   Ea = exp2(C2*aq), Ek = exp2(C2*keys), C2 = 2*log2(e)
// R12: GEMMs BK=64 + reg prefetch; ctx GEMM is now batched bf16 MFMA
// (softmax-only kernel writes pbf; keys batch-transposed to kbfT).

#define C2 2.88539008177792681f

typedef unsigned short u16;
typedef short s16x8 __attribute__((ext_vector_type(8)));
typedef float f32x4 __attribute__((ext_vector_type(4)));

__device__ __forceinline__ float fast_rcp(float x) { return __builtin_amdgcn_rcpf(x); }

__device__ __forceinline__ u16 f2bf(float f) {
  union { float f; unsigned u; } v; v.f = f;
  unsigned r = v.u + 0x7fffu + ((v.u >> 16) & 1u);
  return (u16)(r >> 16);
}
__device__ __forceinline__ unsigned packbf(float a, float b) {
  return (unsigned)f2bf(a) | ((unsigned)f2bf(b) << 16);
}

// ---------------------------------------------------------------------------
// Prep: blocks [0,2048): Ek = exp2(C2*keys) (block 0 also: Cout=sum(w)+b).
// Blocks [2048,3072): qbf = bf16(query).
// ---------------------------------------------------------------------------
__global__ __launch_bounds__(256) void prep_kernel(
    const float* __restrict__ keys, float* __restrict__ Ek,
    const float* __restrict__ query, u16* __restrict__ qbf,
    const float* __restrict__ w_att, const float* __restrict__ b_att,
    float* __restrict__ Cout)
{
  __shared__ float red[4];
  const int t = threadIdx.x;
  const int bx = blockIdx.x;
  if (bx < 2048) {
    const size_t i4 = (size_t)bx * 256 + t;
    float4 v = ((const float4*)keys)[i4];
    float4 o;
    o.x = exp2f(C2 * v.x); o.y = exp2f(C2 * v.y);
    o.z = exp2f(C2 * v.z); o.w = exp2f(C2 * v.w);
    ((float4*)Ek)[i4] = o;
    if (bx == 0) {
      float wsum = w_att[t] + w_att[t + 256];
#pragma unroll
      for (int m = 32; m; m >>= 1) wsum += __shfl_xor(wsum, m);
      if ((t & 63) == 0) red[t >> 6] = wsum;
      __syncthreads();
      if (t == 0) Cout[0] = red[0] + red[1] + red[2] + red[3] + b_att[0];
    }
  } else {
    const size_t i8 = ((size_t)(bx - 2048) * 256 + t) * 8;
    float4 a = *(const float4*)&query[i8];
    float4 b = *(const float4*)&query[i8 + 4];
    unsigned p0 = packbf(a.x, a.y), p1 = packbf(a.z, a.w);
    unsigned p2 = packbf(b.x, b.y), p3 = packbf(b.z, b.w);
    *(int4*)&qbf[i8] = make_int4(p0, p1, p2, p3);
  }
}

// ---------------------------------------------------------------------------
// Prep: bf16-transpose Wq ([512][512]) and Wout ([1024][512]). grid (16,48).
// ---------------------------------------------------------------------------
__global__ __launch_bounds__(256) void transpose_w_bf16(
    const float* __restrict__ Wq, u16* __restrict__ Wqt,
    const float* __restrict__ Wout, u16* __restrict__ Woutt)
{
  __shared__ u16 tile[32][40];
  const int t = threadIdx.x;
  const int by = blockIdx.y;
  const float* W; u16* Wt; int K, k0;
  if (by < 16) { W = Wq;   Wt = Wqt;   K = 512;  k0 = by * 32; }
  else         { W = Wout; Wt = Woutt; K = 1024; k0 = (by - 16) * 32; }
  const int n0 = blockIdx.x * 32;
  const int r = t >> 3, c = (t & 7) * 4;
  float4 v = *(const float4*)&W[(size_t)(k0 + r) * 512 + n0 + c];
  tile[c + 0][r] = f2bf(v.x); tile[c + 1][r] = f2bf(v.y);
  tile[c + 2][r] = f2bf(v.z); tile[c + 3][r] = f2bf(v.w);
  __syncthreads();
  if (t < 128) {
    const int row = t >> 2, ch = (t & 3) * 8;
    unsigned p0 = (unsigned)tile[row][ch + 0] | ((unsigned)tile[row][ch + 1] << 16);
    unsigned p1 = (unsigned)tile[row][ch + 2] | ((unsigned)tile[row][ch + 3] << 16);
    unsigned p2 = (unsigned)tile[row][ch + 4] | ((unsigned)tile[row][ch + 5] << 16);
    unsigned p3 = (unsigned)tile[row][ch + 6] | ((unsigned)tile[row][ch + 7] << 16);
    *(int4*)&Wt[(size_t)(n0 + row) * K + k0 + ch] = make_int4(p0, p1, p2, p3);
  }
}

// ---------------------------------------------------------------------------
// Transpose keys per batch: kbfT[b][n][k] = bf16(keys[b][k][n]).
// grid (16, 8, 16): n0=bx*32, k0=by*32, b=bz.
// ---------------------------------------------------------------------------
__global__ __launch_bounds__(256) void transpose_keys_bf16(
    const float* __restrict__ keys, u16* __restrict__ kbfT)
{
  __shared__ u16 tile[32][40];
  const int t = threadIdx.x;
  const int n0 = blockIdx.x * 32, k0 = blockIdx.y * 32, b = blockIdx.z;
  const float* src = keys + (size_t)b * 131072;
  u16* dst = kbfT + (size_t)b * 131072;
  const int r = t >> 3, c = (t & 7) * 4;
  float4 v = *(const float4*)&src[(size_t)(k0 + r) * 512 + n0 + c];
  tile[c + 0][r] = f2bf(v.x); tile[c + 1][r] = f2bf(v.y);
  tile[c + 2][r] = f2bf(v.z); tile[c + 3][r] = f2bf(v.w);
  __syncthreads();
  if (t < 128) {
    const int row = t >> 2, ch = (t & 3) * 8;
    unsigned p0 = (unsigned)tile[row][ch + 0] | ((unsigned)tile[row][ch + 1] << 16);
    unsigned p1 = (unsigned)tile[row][ch + 2] | ((unsigned)tile[row][ch + 3] << 16);
    unsigned p2 = (unsigned)tile[row][ch + 4] | ((unsigned)tile[row][ch + 5] << 16);
    unsigned p3 = (unsigned)tile[row][ch + 6] | ((unsigned)tile[row][ch + 7] << 16);
    *(int4*)&dst[(size_t)(n0 + row) * 256 + k0 + ch] = make_int4(p0, p1, p2, p3);
  }
}

// ---------------------------------------------------------------------------
// K1/K4: bf16 MFMA GEMM, BK=64, register prefetch of next K-step.
// C[M][512] = act(A @ W + bias). A bf16 split A0/A1 at kSplit, stride 512.
// Bt bf16 [512 n][K k]. Tile 64x64, 4 waves (2x2), wave tile 32x32.
// LDS rows padded to 72 elems (144B): 2-way banks (free).
// ---------------------------------------------------------------------------
__global__ __launch_bounds__(256) void gemm_mfma_bf16(
    const u16* __restrict__ A0, const u16* __restrict__ A1, int kSplit,
    const u16* __restrict__ Bt, const float* __restrict__ bias,
    float* __restrict__ C, int K, int act)
{
  __shared__ u16 As[64 * 72];
  __shared__ u16 Bs[64 * 72];
  const int t = threadIdx.x;
  const int lane = t & 63, wid = t >> 6;
  const int wm = wid >> 1, wn = wid & 1;
  const int col0 = blockIdx.x * 64, row0 = blockIdx.y * 64;
  const int lr = t >> 2, lc = (t & 3) * 16;  // staging row, 16-elem chunk
  const int fr = lane & 15, fg = (lane >> 4) * 8;

  f32x4 acc[2][2] = {};
  const int nIter = K >> 6;

  int4 a0v, a1v, b0v, b1v;
  {
    const u16* Asrc = (0 < kSplit) ? A0 : A1;
    a0v = *(const int4*)&Asrc[(size_t)(row0 + lr) * 512 + lc];
    a1v = *(const int4*)&Asrc[(size_t)(row0 + lr) * 512 + lc + 8];
    b0v = *(const int4*)&Bt[(size_t)(col0 + lr) * K + lc];
    b1v = *(const int4*)&Bt[(size_t)(col0 + lr) * K + lc + 8];
  }
  for (int it = 0; it < nIter; ++it) {
    __syncthreads();
    *(int4*)&As[lr * 72 + lc]     = a0v;
    *(int4*)&As[lr * 72 + lc + 8] = a1v;
    *(int4*)&Bs[lr * 72 + lc]     = b0v;
    *(int4*)&Bs[lr * 72 + lc + 8] = b1v;
    __syncthreads();

    if (it + 1 < nIter) {  // prefetch next K-step; hides under MFMA below
      const int k0 = (it + 1) << 6;
      const u16* Asrc; int kc;
      if (k0 < kSplit) { Asrc = A0; kc = k0; } else { Asrc = A1; kc = k0 - kSplit; }
      a0v = *(const int4*)&Asrc[(size_t)(row0 + lr) * 512 + kc + lc];
      a1v = *(const int4*)&Asrc[(size_t)(row0 + lr) * 512 + kc + lc + 8];
      b0v = *(const int4*)&Bt[(size_t)(col0 + lr) * K + k0 + lc];
      b1v = *(const int4*)&Bt[(size_t)(col0 + lr) * K + k0 + lc + 8];
    }

#pragma unroll
    for (int ks = 0; ks < 2; ++ks) {
      s16x8 af[2], bf[2];
#pragma unroll
      for (int m = 0; m < 2; ++m)
        af[m] = *(const s16x8*)&As[(wm * 32 + m * 16 + fr) * 72 + ks * 32 + fg];
#pragma unroll
      for (int n = 0; n < 2; ++n)
        bf[n] = *(const s16x8*)&Bs[(wn * 32 + n * 16 + fr) * 72 + ks * 32 + fg];
#pragma unroll
      for (int m = 0; m < 2; ++m)
#pragma unroll
        for (int n = 0; n < 2; ++n)
          acc[m][n] = __builtin_amdgcn_mfma_f32_16x16x32_bf16(af[m], bf[n], acc[m][n], 0, 0, 0);
    }
  }

  const int fq = lane >> 4;
#pragma unroll
  for (int n = 0; n < 2; ++n) {
    const int col = col0 + wn * 32 + n * 16 + fr;
    const float bv = bias[col];
#pragma unroll
    for (int m = 0; m < 2; ++m) {
#pragma unroll
      for (int i = 0; i < 4; ++i) {
        const int row = row0 + wm * 32 + m * 16 + fq * 4 + i;
        float v = acc[m][n][i] + bv;
        if (act == 1) {
          float e = __expf(2.0f * v);
          v = 1.0f - 2.0f * fast_rcp(e + 1.0f);
        } else if (act == 2) {
          v = exp2f(C2 * v);
        }
        C[(size_t)row * 512 + col] = v;
      }
    }
  }
}

// ---------------------------------------------------------------------------
// K2: partial scores over an n-QUARTER (128). grid (4,4,64). R7 config.
// ---------------------------------------------------------------------------
__global__ __launch_bounds__(256) void score_kernel(
    const float* __restrict__ Ea, const float* __restrict__ Ek,
    const float* __restrict__ w_att, const float* __restrict__ Cptr,
    float* __restrict__ S)
{
  __shared__ float ea_s[64][68];
  __shared__ float ek_s[64][68];
  __shared__ float w_s[128];

  const int z = blockIdx.z;
  const int b = z >> 2, qt = z & 3;
  const int q0 = blockIdx.y * 64, k0 = blockIdx.x * 64;
  const int t = threadIdx.x;
  if (t < 128) w_s[t] = w_att[qt * 128 + t];

  const int qi = t >> 4, ki = t & 15;
  const int lr = t >> 2, lc = (t & 3) * 16;
  const float* eap = Ea + (size_t)(b * 256 + q0) * 512 + qt * 128;
  const float* ekp = Ek + (size_t)(b * 256 + k0) * 512 + qt * 128;

  float acc[4][4] = {};

  for (int c = 0; c < 2; ++c) {
    const int gb = lr * 512 + c * 64 + lc;
    float4 A0 = *(const float4*)&eap[gb + 0];
    float4 A1 = *(const float4*)&eap[gb + 4];
    float4 A2 = *(const float4*)&eap[gb + 8];
    float4 A3 = *(const float4*)&eap[gb + 12];
    float4 K0 = *(const float4*)&ekp[gb + 0];
    float4 K1 = *(const float4*)&ekp[gb + 4];
    float4 K2 = *(const float4*)&ekp[gb + 8];
    float4 K3 = *(const float4*)&ekp[gb + 12];
    __syncthreads();
    *(float4*)&ea_s[lr][lc + 0]  = A0;
    *(float4*)&ea_s[lr][lc + 4]  = A1;
    *(float4*)&ea_s[lr][lc + 8]  = A2;
    *(float4*)&ea_s[lr][lc + 12] = A3;
    *(float4*)&ek_s[lr][lc + 0]  = K0;
    *(float4*)&ek_s[lr][lc + 4]  = K1;
    *(float4*)&ek_s[lr][lc + 8]  = K2;
    *(float4*)&ek_s[lr][lc + 12] = K3;
    __syncthreads();

    for (int j = 0; j < 64; j += 4) {
      float4 av[4], kv[4];
#pragma unroll
      for (int m = 0; m < 4; ++m) av[m] = *(const float4*)&ea_s[qi + m * 16][j];
#pragma unroll
      for (int n = 0; n < 4; ++n) kv[n] = *(const float4*)&ek_s[ki + n * 16][j];
      float4 wv = *(const float4*)&w_s[c * 64 + j];
#pragma unroll
      for (int m = 0; m < 4; ++m) {
#pragma unroll
        for (int n = 0; n < 4; ++n) {
          float q1 = fmaf(av[m].x, kv[n].x, 1.0f);
          float q2 = fmaf(av[m].y, kv[n].y, 1.0f);
          float q3 = fmaf(av[m].z, kv[n].z, 1.0f);
          float q4 = fmaf(av[m].w, kv[n].w, 1.0f);
          float N12 = fmaf(wv.x, q2, wv.y * q1);
          float D12 = q1 * q2;
          float N34 = fmaf(wv.z, q4, wv.w * q3);
          float D34 = q3 * q4;
          float Nt = fmaf(N12, D34, N34 * D12);
          float Dt = D12 * D34;
          acc[m][n] = fmaf(Nt, fast_rcp(Dt), acc[m][n]);
        }
      }
    }
  }

  const float Cv = (qt == 0) ? Cptr[0] : 0.0f;
  float* sc = S + (size_t)qt * 1048576;
#pragma unroll
  for (int m = 0; m < 4; ++m) {
    const size_t qr = (size_t)(b * 256 + q0 + qi + m * 16);
#pragma unroll
    for (int n = 0; n < 4; ++n)
      sc[qr * 256 + k0 + ki + n * 16] = fmaf(-2.f, acc[m][n], Cv);
  }
}

// ---------------------------------------------------------------------------
// K3a: softmax-only. One wave per q-row (4 rows/block, grid 1024).
// Reads 4 S partials, writes p_out (f32) and pbf (bf16).
// ---------------------------------------------------------------------------
__global__ __launch_bounds__(256) void softmax_kernel(
    const float* __restrict__ S, float* __restrict__ p_out,
    u16* __restrict__ pbf)
{
  const int t = threadIdx.x;
  const int w = t >> 6, lane = t & 63;
  const int row = blockIdx.x * 4 + w;
  const size_t off = (size_t)row * 256 + lane * 4;
  float4 sa = *(const float4*)&S[off];
  float4 sb = *(const float4*)&S[off + 1048576];
  float4 sc = *(const float4*)&S[off + 2097152];
  float4 sd = *(const float4*)&S[off + 3145728];
  float4 s4 = {(sa.x + sb.x) + (sc.x + sd.x), (sa.y + sb.y) + (sc.y + sd.y),
               (sa.z + sb.z) + (sc.z + sd.z), (sa.w + sb.w) + (sc.w + sd.w)};
  float m = fmaxf(fmaxf(s4.x, s4.y), fmaxf(s4.z, s4.w));
#pragma unroll
  for (int msk = 32; msk; msk >>= 1) m = fmaxf(m, __shfl_xor(m, msk));
  float e0 = __expf(s4.x - m);
  float e1 = __expf(s4.y - m);
  float e2 = __expf(s4.z - m);
  float e3 = __expf(s4.w - m);
  float ssum = (e0 + e1) + (e2 + e3);
#pragma unroll
  for (int msk = 32; msk; msk >>= 1) ssum += __shfl_xor(ssum, msk);
  float rs = 1.0f / ssum;
  float4 p4 = {e0 * rs, e1 * rs, e2 * rs, e3 * rs};
  *(float4*)&p_out[off] = p4;
  unsigned lo = packbf(p4.x, p4.y), hi = packbf(p4.z, p4.w);
  *(int2*)&pbf[off] = make_int2(lo, hi);
}

// ---------------------------------------------------------------------------
// K3b: ctx(bf16) = pbf @ kbfT per batch. MFMA, tile 64x64, BK=64, K=256.
// grid (8, 4, 16): col0=bx*64, row0=by*64 (in-batch), b=bz.
// ---------------------------------------------------------------------------
__global__ __launch_bounds__(256) void ctx_gemm(
    const u16* __restrict__ pbf, const u16* __restrict__ kbfT,
    u16* __restrict__ ctxbf)
{
  __shared__ u16 As[64 * 72];
  __shared__ u16 Bs[64 * 72];
  const int t = threadIdx.x;
  const int lane = t & 63, wid = t >> 6;
  const int wm = wid >> 1, wn = wid & 1;
  const int col0 = blockIdx.x * 64, row0 = blockIdx.y * 64, b = blockIdx.z;
  const u16* A = pbf + (size_t)b * 65536;    // [256 q][256 k]
  const u16* Bm = kbfT + (size_t)b * 131072; // [512 n][256 k]
  const int lr = t >> 2, lc = (t & 3) * 16;
  const int fr = lane & 15, fg = (lane >> 4) * 8;

  f32x4 acc[2][2] = {};

  int4 a0v = *(const int4*)&A[(size_t)(row0 + lr) * 256 + lc];
  int4 a1v = *(const int4*)&A[(size_t)(row0 + lr) * 256 + lc + 8];
  int4 b0v = *(const int4*)&Bm[(size_t)(col0 + lr) * 256 + lc];
  int4 b1v = *(const int4*)&Bm[(size_t)(col0 + lr) * 256 + lc + 8];

  for (int it = 0; it < 4; ++it) {
    __syncthreads();
    *(int4*)&As[lr * 72 + lc]     = a0v;
    *(int4*)&As[lr * 72 + lc + 8] = a1v;
    *(int4*)&Bs[lr * 72 + lc]     = b0v;
    *(int4*)&Bs[lr * 72 + lc + 8] = b1v;
    __syncthreads();

    if (it < 3) {
      const int k0 = (it + 1) << 6;
      a0v = *(const int4*)&A[(size_t)(row0 + lr) * 256 + k0 + lc];
      a1v = *(const int4*)&A[(size_t)(row0 + lr) * 256 + k0 + lc + 8];
      b0v = *(const int4*)&Bm[(size_t)(col0 + lr) * 256 + k0 + lc];
      b1v = *(const int4*)&Bm[(size_t)(col0 + lr) * 256 + k0 + lc + 8];
    }

#pragma unroll
    for (int ks = 0; ks < 2; ++ks) {
      s16x8 af[2], bf[2];
#pragma unroll
      for (int m = 0; m < 2; ++m)
        af[m] = *(const s16x8*)&As[(wm * 32 + m * 16 + fr) * 72 + ks * 32 + fg];
#pragma unroll
      for (int n = 0; n < 2; ++n)
        bf[n] = *(const s16x8*)&Bs[(wn * 32 + n * 16 + fr) * 72 + ks * 32 + fg];
#pragma unroll
      for (int m = 0; m < 2; ++m)
#pragma unroll
        for (int n = 0; n < 2; ++n)
          acc[m][n] = __builtin_amdgcn_mfma_f32_16x16x32_bf16(af[m], bf[n], acc[m][n], 0, 0, 0);
    }
  }

  const int fq = lane >> 4;
#pragma unroll
  for (int n = 0; n < 2; ++n) {
    const int col = col0 + wn * 32 + n * 16 + fr;
#pragma unroll
    for (int m = 0; m < 2; ++m) {
#pragma unroll
      for (int i = 0; i < 4; ++i) {
        const int row = row0 + wm * 32 + m * 16 + fq * 4 + i;
        ctxbf[(size_t)(b * 256 + row) * 512 + col] = f2bf(acc[m][n][i]);
      }
    }
  }
}

// ---------------------------------------------------------------------------
extern "C" void kernel_launch(void* const* d_in, const int* in_sizes, int n_in,
                              void* d_out, int out_size, void* d_ws, size_t ws_size,
                              hipStream_t stream) {
  const float* query = (const float*)d_in[0];
  const float* keys  = (const float*)d_in[1];
  const float* Wq    = (const float*)d_in[2];
  const float* bq    = (const float*)d_in[3];
  const float* w_att = (const float*)d_in[4];
  const float* b_att = (const float*)d_in[5];
  const float* Wout  = (const float*)d_in[6];
  const float* bout  = (const float*)d_in[7];

  float* out_tanh = (float*)d_out;                  // [4096][512]
  float* out_p    = out_tanh + (size_t)4096 * 512;  // [4096][256]

  float* ws = (float*)d_ws;
  float* Ea     = ws;                    // [4096][512] f32 (dead after K2)
  float* Ek     = ws + 2097152;          // [4096][512] f32 (dead after K2)
  float* S      = ws + 4194304;          // [4][4096][256] f32 (dead after K3a)
  float* Cptr   = ws + 8388608;          // [1] (+pad to 16)
  u16*   Wqt    = (u16*)(ws + 8388624);  // [512][512] bf16
  u16*   Woutt  = Wqt + 262144;          // [512][1024] bf16
  u16*   qbf    = Woutt + 524288;        // [4096][512] bf16
  u16*   ctxbf  = (u16*)Ea;              // [4096][512] bf16, aliases dead Ea
  u16*   kbfT   = (u16*)Ek;              // [16][512][256] bf16, aliases dead Ek
  u16*   pbf    = kbfT + 2097152;        // [16][256][256] bf16, still in Ek

  // Prep: Ek + Cptr + qbf; transposed bf16 weights
  prep_kernel<<<3072, 256, 0, stream>>>(keys, Ek, query, qbf, w_att, b_att, Cptr);
  transpose_w_bf16<<<dim3(16, 48), 256, 0, stream>>>(Wq, Wqt, Wout, Woutt);

  // K1: Ea = exp2(C2 * (qbf @ Wq + bq))   [MFMA bf16, BK=64]
  gemm_mfma_bf16<<<dim3(8, 64), 256, 0, stream>>>(
      qbf, qbf, 512, Wqt, bq, Ea, 512, 2);

  // K2: partial scores (4 n-quarters), R7 config
  score_kernel<<<dim3(4, 4, 64), 256, 0, stream>>>(
      Ea, Ek, w_att, Cptr, S);

  // keys^T bf16 (overwrites dead Ek region)
  transpose_keys_bf16<<<dim3(16, 8, 16), 256, 0, stream>>>(keys, kbfT);

  // K3a: softmax (writes p fp32 + pbf bf16)
  softmax_kernel<<<1024, 256, 0, stream>>>(S, out_p, pbf);

  // K3b: ctxbf = pbf @ kbfT   [batched MFMA bf16]
  ctx_gemm<<<dim3(8, 4, 16), 256, 0, stream>>>(pbf, kbfT, ctxbf);

  // K4: out = tanh(concat(qbf, ctxbf) @ Wout + bout)   [MFMA bf16, BK=64]
  gemm_mfma_bf16<<<dim3(8, 64), 256, 0, stream>>>(
      qbf, ctxbf, 512, Woutt, bout, out_tanh, 1024, 1);
}

// Round 13
// 101.007 us; speedup vs baseline: 1.7407x; 1.0156x over previous
//
#include <hip/hip_runtime.h>

// Problem constants: B=16, TQ=256, TK=256, QD=512, KD=512
// d_out = [ tanh_out: 16*256*512 f32 ; p: 16*256*256 f32 ]
// scores[b,q,k] = (sum_n w_n + b_att) - 2 * sum_n w_n / (1 + Ea[q,n]*Ek[k,n])
//   Ea = exp2(C2*aq), Ek = exp2(C2*keys), C2 = 2*log2(e)
// R13: score inner math on f32x2 (targets v_pk_fma_f32/v_pk_mul_f32, CDNA
// packed fp32) with interleaved pair-grouping; w via uniform scalar loads;
// prep kernels fused into one launch.

#define C2 2.88539008177792681f

typedef unsigned short u16;
typedef short s16x8 __attribute__((ext_vector_type(8)));
typedef float f32x4 __attribute__((ext_vector_type(4)));
typedef float f32x2 __attribute__((ext_vector_type(2)));

__device__ __forceinline__ float fast_rcp(float x) { return __builtin_amdgcn_rcpf(x); }
__device__ __forceinline__ f32x2 fma2(f32x2 a, f32x2 b, f32x2 c) {
  return __builtin_elementwise_fma(a, b, c);
}

__device__ __forceinline__ u16 f2bf(float f) {
  union { float f; unsigned u; } v; v.f = f;
  unsigned r = v.u + 0x7fffu + ((v.u >> 16) & 1u);
  return (u16)(r >> 16);
}
__device__ __forceinline__ unsigned packbf(float a, float b) {
  return (unsigned)f2bf(a) | ((unsigned)f2bf(b) << 16);
}

// ---------------------------------------------------------------------------
// Mega-prep, one launch (5888 blocks):
//  [0,2048):     Ek = exp2(C2*keys); block 0 also Cptr = sum(w)+b_att
//  [2048,3072):  qbf = bf16(query)
//  [3072,5120):  kbfT[b][n][k] = bf16(keys[b][k][n])
//  [5120,5888):  Wqt / Woutt = bf16(W^T)
// ---------------------------------------------------------------------------
__global__ __launch_bounds__(256) void mega_prep(
    const float* __restrict__ keys, float* __restrict__ Ek,
    const float* __restrict__ query, u16* __restrict__ qbf,
    u16* __restrict__ kbfT,
    const float* __restrict__ Wq, u16* __restrict__ Wqt,
    const float* __restrict__ Wout, u16* __restrict__ Woutt,
    const float* __restrict__ w_att, const float* __restrict__ b_att,
    float* __restrict__ Cptr)
{
  __shared__ float red[4];
  __shared__ u16 tile[32][40];
  const int t = threadIdx.x;
  const int bx = blockIdx.x;

  if (bx < 2048) {
    const size_t i4 = (size_t)bx * 256 + t;
    float4 v = ((const float4*)keys)[i4];
    float4 o;
    o.x = exp2f(C2 * v.x); o.y = exp2f(C2 * v.y);
    o.z = exp2f(C2 * v.z); o.w = exp2f(C2 * v.w);
    ((float4*)Ek)[i4] = o;
    if (bx == 0) {
      float wsum = w_att[t] + w_att[t + 256];
#pragma unroll
      for (int m = 32; m; m >>= 1) wsum += __shfl_xor(wsum, m);
      if ((t & 63) == 0) red[t >> 6] = wsum;
      __syncthreads();
      if (t == 0) Cptr[0] = red[0] + red[1] + red[2] + red[3] + b_att[0];
    }
  } else if (bx < 3072) {
    const size_t i8 = ((size_t)(bx - 2048) * 256 + t) * 8;
    float4 a = *(const float4*)&query[i8];
    float4 b = *(const float4*)&query[i8 + 4];
    unsigned p0 = packbf(a.x, a.y), p1 = packbf(a.z, a.w);
    unsigned p2 = packbf(b.x, b.y), p3 = packbf(b.z, b.w);
    *(int4*)&qbf[i8] = make_int4(p0, p1, p2, p3);
  } else if (bx < 5120) {
    const int b2 = bx - 3072;
    const int n0 = (b2 & 15) * 32, k0 = ((b2 >> 4) & 7) * 32, b = b2 >> 7;
    const float* src = keys + (size_t)b * 131072;
    u16* dst = kbfT + (size_t)b * 131072;
    const int r = t >> 3, c = (t & 7) * 4;
    float4 v = *(const float4*)&src[(size_t)(k0 + r) * 512 + n0 + c];
    tile[c + 0][r] = f2bf(v.x); tile[c + 1][r] = f2bf(v.y);
    tile[c + 2][r] = f2bf(v.z); tile[c + 3][r] = f2bf(v.w);
    __syncthreads();
    if (t < 128) {
      const int row = t >> 2, ch = (t & 3) * 8;
      unsigned p0 = (unsigned)tile[row][ch + 0] | ((unsigned)tile[row][ch + 1] << 16);
      unsigned p1 = (unsigned)tile[row][ch + 2] | ((unsigned)tile[row][ch + 3] << 16);
      unsigned p2 = (unsigned)tile[row][ch + 4] | ((unsigned)tile[row][ch + 5] << 16);
      unsigned p3 = (unsigned)tile[row][ch + 6] | ((unsigned)tile[row][ch + 7] << 16);
      *(int4*)&dst[(size_t)(n0 + row) * 256 + k0 + ch] = make_int4(p0, p1, p2, p3);
    }
  } else {
    const int b3 = bx - 5120;
    const int by = b3 >> 4;
    const int n0 = (b3 & 15) * 32;
    const float* W; u16* Wt; int K, k0;
    if (by < 16) { W = Wq;   Wt = Wqt;   K = 512;  k0 = by * 32; }
    else         { W = Wout; Wt = Woutt; K = 1024; k0 = (by - 16) * 32; }
    const int r = t >> 3, c = (t & 7) * 4;
    float4 v = *(const float4*)&W[(size_t)(k0 + r) * 512 + n0 + c];
    tile[c + 0][r] = f2bf(v.x); tile[c + 1][r] = f2bf(v.y);
    tile[c + 2][r] = f2bf(v.z); tile[c + 3][r] = f2bf(v.w);
    __syncthreads();
    if (t < 128) {
      const int row = t >> 2, ch = (t & 3) * 8;
      unsigned p0 = (unsigned)tile[row][ch + 0] | ((unsigned)tile[row][ch + 1] << 16);
      unsigned p1 = (unsigned)tile[row][ch + 2] | ((unsigned)tile[row][ch + 3] << 16);
      unsigned p2 = (unsigned)tile[row][ch + 4] | ((unsigned)tile[row][ch + 5] << 16);
      unsigned p3 = (unsigned)tile[row][ch + 6] | ((unsigned)tile[row][ch + 7] << 16);
      *(int4*)&Wt[(size_t)(n0 + row) * K + k0 + ch] = make_int4(p0, p1, p2, p3);
    }
  }
}

// ---------------------------------------------------------------------------
// K1/K4: bf16 MFMA GEMM, BK=64, register prefetch. Tile 64x64, 4 waves.
// LDS rows padded to 72 elems (144B): 2-way banks (free).
// ---------------------------------------------------------------------------
__global__ __launch_bounds__(256) void gemm_mfma_bf16(
    const u16* __restrict__ A0, const u16* __restrict__ A1, int kSplit,
    const u16* __restrict__ Bt, const float* __restrict__ bias,
    float* __restrict__ C, int K, int act)
{
  __shared__ u16 As[64 * 72];
  __shared__ u16 Bs[64 * 72];
  const int t = threadIdx.x;
  const int lane = t & 63, wid = t >> 6;
  const int wm = wid >> 1, wn = wid & 1;
  const int col0 = blockIdx.x * 64, row0 = blockIdx.y * 64;
  const int lr = t >> 2, lc = (t & 3) * 16;
  const int fr = lane & 15, fg = (lane >> 4) * 8;

  f32x4 acc[2][2] = {};
  const int nIter = K >> 6;

  int4 a0v, a1v, b0v, b1v;
  {
    const u16* Asrc = (0 < kSplit) ? A0 : A1;
    a0v = *(const int4*)&Asrc[(size_t)(row0 + lr) * 512 + lc];
    a1v = *(const int4*)&Asrc[(size_t)(row0 + lr) * 512 + lc + 8];
    b0v = *(const int4*)&Bt[(size_t)(col0 + lr) * K + lc];
    b1v = *(const int4*)&Bt[(size_t)(col0 + lr) * K + lc + 8];
  }
  for (int it = 0; it < nIter; ++it) {
    __syncthreads();
    *(int4*)&As[lr * 72 + lc]     = a0v;
    *(int4*)&As[lr * 72 + lc + 8] = a1v;
    *(int4*)&Bs[lr * 72 + lc]     = b0v;
    *(int4*)&Bs[lr * 72 + lc + 8] = b1v;
    __syncthreads();

    if (it + 1 < nIter) {
      const int k0 = (it + 1) << 6;
      const u16* Asrc; int kc;
      if (k0 < kSplit) { Asrc = A0; kc = k0; } else { Asrc = A1; kc = k0 - kSplit; }
      a0v = *(const int4*)&Asrc[(size_t)(row0 + lr) * 512 + kc + lc];
      a1v = *(const int4*)&Asrc[(size_t)(row0 + lr) * 512 + kc + lc + 8];
      b0v = *(const int4*)&Bt[(size_t)(col0 + lr) * K + k0 + lc];
      b1v = *(const int4*)&Bt[(size_t)(col0 + lr) * K + k0 + lc + 8];
    }

#pragma unroll
    for (int ks = 0; ks < 2; ++ks) {
      s16x8 af[2], bf[2];
#pragma unroll
      for (int m = 0; m < 2; ++m)
        af[m] = *(const s16x8*)&As[(wm * 32 + m * 16 + fr) * 72 + ks * 32 + fg];
#pragma unroll
      for (int n = 0; n < 2; ++n)
        bf[n] = *(const s16x8*)&Bs[(wn * 32 + n * 16 + fr) * 72 + ks * 32 + fg];
#pragma unroll
      for (int m = 0; m < 2; ++m)
#pragma unroll
        for (int n = 0; n < 2; ++n)
          acc[m][n] = __builtin_amdgcn_mfma_f32_16x16x32_bf16(af[m], bf[n], acc[m][n], 0, 0, 0);
    }
  }

  const int fq = lane >> 4;
#pragma unroll
  for (int n = 0; n < 2; ++n) {
    const int col = col0 + wn * 32 + n * 16 + fr;
    const float bv = bias[col];
#pragma unroll
    for (int m = 0; m < 2; ++m) {
#pragma unroll
      for (int i = 0; i < 4; ++i) {
        const int row = row0 + wm * 32 + m * 16 + fq * 4 + i;
        float v = acc[m][n][i] + bv;
        if (act == 1) {
          float e = __expf(2.0f * v);
          v = 1.0f - 2.0f * fast_rcp(e + 1.0f);
        } else if (act == 2) {
          v = exp2f(C2 * v);
        }
        C[(size_t)row * 512 + col] = v;
      }
    }
  }
}

// ---------------------------------------------------------------------------
// K2: partial scores over an n-QUARTER (128). grid (4,4,64). R7 tiling
// (64x64, 4x4 microtile, [64][68] LDS) with PACKED-FP32 inner math:
// j-steps of 8 elems as 4 f32x2 pairs (interleaved grouping; both pair
// lanes sum into the same score). w via uniform scalar loads (no LDS).
// ---------------------------------------------------------------------------
__global__ __launch_bounds__(256) void score_kernel(
    const float* __restrict__ Ea, const float* __restrict__ Ek,
    const float* __restrict__ w_att, const float* __restrict__ Cptr,
    float* __restrict__ S)
{
  __shared__ float ea_s[64][68];
  __shared__ float ek_s[64][68];

  const int z = blockIdx.z;
  const int b = z >> 2, qt = z & 3;
  const int q0 = blockIdx.y * 64, k0 = blockIdx.x * 64;
  const int t = threadIdx.x;

  const int qi = t >> 4, ki = t & 15;
  const int lr = t >> 2, lc = (t & 3) * 16;
  const float* eap = Ea + (size_t)(b * 256 + q0) * 512 + qt * 128;
  const float* ekp = Ek + (size_t)(b * 256 + k0) * 512 + qt * 128;
  const float* wbase = w_att + qt * 128;  // uniform -> scalar loads

  float acc[4][4] = {};
  const f32x2 one = {1.0f, 1.0f};

  for (int c = 0; c < 2; ++c) {
    const int gb = lr * 512 + c * 64 + lc;
    float4 A0 = *(const float4*)&eap[gb + 0];
    float4 A1 = *(const float4*)&eap[gb + 4];
    float4 A2 = *(const float4*)&eap[gb + 8];
    float4 A3 = *(const float4*)&eap[gb + 12];
    float4 K0 = *(const float4*)&ekp[gb + 0];
    float4 K1 = *(const float4*)&ekp[gb + 4];
    float4 K2 = *(const float4*)&ekp[gb + 8];
    float4 K3 = *(const float4*)&ekp[gb + 12];
    __syncthreads();  // prev chunk consumed
    *(float4*)&ea_s[lr][lc + 0]  = A0;
    *(float4*)&ea_s[lr][lc + 4]  = A1;
    *(float4*)&ea_s[lr][lc + 8]  = A2;
    *(float4*)&ea_s[lr][lc + 12] = A3;
    *(float4*)&ek_s[lr][lc + 0]  = K0;
    *(float4*)&ek_s[lr][lc + 4]  = K1;
    *(float4*)&ek_s[lr][lc + 8]  = K2;
    *(float4*)&ek_s[lr][lc + 12] = K3;
    __syncthreads();

    for (int j = 0; j < 64; j += 8) {
      // k pairs for 4 n-columns
      f32x2 kp[4][4];
#pragma unroll
      for (int n = 0; n < 4; ++n) {
        float4 kv0 = *(const float4*)&ek_s[ki + n * 16][j];
        float4 kv1 = *(const float4*)&ek_s[ki + n * 16][j + 4];
        kp[n][0] = f32x2{kv0.x, kv0.y};
        kp[n][1] = f32x2{kv0.z, kv0.w};
        kp[n][2] = f32x2{kv1.x, kv1.y};
        kp[n][3] = f32x2{kv1.z, kv1.w};
      }
      // w pairs (wave-uniform scalar loads)
      const float* wq = wbase + c * 64 + j;
      f32x2 wp0 = {wq[0], wq[1]};
      f32x2 wp1 = {wq[2], wq[3]};
      f32x2 wp2 = {wq[4], wq[5]};
      f32x2 wp3 = {wq[6], wq[7]};

#pragma unroll
      for (int m = 0; m < 4; ++m) {
        float4 av0 = *(const float4*)&ea_s[qi + m * 16][j];
        float4 av1 = *(const float4*)&ea_s[qi + m * 16][j + 4];
        f32x2 ap0 = {av0.x, av0.y};
        f32x2 ap1 = {av0.z, av0.w};
        f32x2 ap2 = {av1.x, av1.y};
        f32x2 ap3 = {av1.z, av1.w};
#pragma unroll
        for (int n = 0; n < 4; ++n) {
          f32x2 q1 = fma2(ap0, kp[n][0], one);
          f32x2 q2 = fma2(ap1, kp[n][1], one);
          f32x2 q3 = fma2(ap2, kp[n][2], one);
          f32x2 q4 = fma2(ap3, kp[n][3], one);
          f32x2 N12 = fma2(wp0, q2, wp1 * q1);
          f32x2 D12 = q1 * q2;
          f32x2 N34 = fma2(wp2, q4, wp3 * q3);
          f32x2 D34 = q3 * q4;
          f32x2 Nt = fma2(N12, D34, N34 * D12);
          f32x2 Dt = D12 * D34;
          float r0 = fast_rcp(Dt.x);
          float r1 = fast_rcp(Dt.y);
          acc[m][n] = fmaf(Nt.x, r0, acc[m][n]);
          acc[m][n] = fmaf(Nt.y, r1, acc[m][n]);
        }
      }
    }
  }

  const float Cv = (qt == 0) ? Cptr[0] : 0.0f;
  float* sc = S + (size_t)qt * 1048576;
#pragma unroll
  for (int m = 0; m < 4; ++m) {
    const size_t qr = (size_t)(b * 256 + q0 + qi + m * 16);
#pragma unroll
    for (int n = 0; n < 4; ++n)
      sc[qr * 256 + k0 + ki + n * 16] = fmaf(-2.f, acc[m][n], Cv);
  }
}

// ---------------------------------------------------------------------------
// K3a: softmax-only. One wave per q-row; writes p_out (f32) and pbf (bf16).
// ---------------------------------------------------------------------------
__global__ __launch_bounds__(256) void softmax_kernel(
    const float* __restrict__ S, float* __restrict__ p_out,
    u16* __restrict__ pbf)
{
  const int t = threadIdx.x;
  const int w = t >> 6, lane = t & 63;
  const int row = blockIdx.x * 4 + w;
  const size_t off = (size_t)row * 256 + lane * 4;
  float4 sa = *(const float4*)&S[off];
  float4 sb = *(const float4*)&S[off + 1048576];
  float4 sc = *(const float4*)&S[off + 2097152];
  float4 sd = *(const float4*)&S[off + 3145728];
  float4 s4 = {(sa.x + sb.x) + (sc.x + sd.x), (sa.y + sb.y) + (sc.y + sd.y),
               (sa.z + sb.z) + (sc.z + sd.z), (sa.w + sb.w) + (sc.w + sd.w)};
  float m = fmaxf(fmaxf(s4.x, s4.y), fmaxf(s4.z, s4.w));
#pragma unroll
  for (int msk = 32; msk; msk >>= 1) m = fmaxf(m, __shfl_xor(m, msk));
  float e0 = __expf(s4.x - m);
  float e1 = __expf(s4.y - m);
  float e2 = __expf(s4.z - m);
  float e3 = __expf(s4.w - m);
  float ssum = (e0 + e1) + (e2 + e3);
#pragma unroll
  for (int msk = 32; msk; msk >>= 1) ssum += __shfl_xor(ssum, msk);
  float rs = 1.0f / ssum;
  float4 p4 = {e0 * rs, e1 * rs, e2 * rs, e3 * rs};
  *(float4*)&p_out[off] = p4;
  unsigned lo = packbf(p4.x, p4.y), hi = packbf(p4.z, p4.w);
  *(int2*)&pbf[off] = make_int2(lo, hi);
}

// ---------------------------------------------------------------------------
// K3b: ctx(bf16) = pbf @ kbfT per batch. MFMA, tile 64x64, BK=64, K=256.
// ---------------------------------------------------------------------------
__global__ __launch_bounds__(256) void ctx_gemm(
    const u16* __restrict__ pbf, const u16* __restrict__ kbfT,
    u16* __restrict__ ctxbf)
{
  __shared__ u16 As[64 * 72];
  __shared__ u16 Bs[64 * 72];
  const int t = threadIdx.x;
  const int lane = t & 63, wid = t >> 6;
  const int wm = wid >> 1, wn = wid & 1;
  const int col0 = blockIdx.x * 64, row0 = blockIdx.y * 64, b = blockIdx.z;
  const u16* A = pbf + (size_t)b * 65536;
  const u16* Bm = kbfT + (size_t)b * 131072;
  const int lr = t >> 2, lc = (t & 3) * 16;
  const int fr = lane & 15, fg = (lane >> 4) * 8;

  f32x4 acc[2][2] = {};

  int4 a0v = *(const int4*)&A[(size_t)(row0 + lr) * 256 + lc];
  int4 a1v = *(const int4*)&A[(size_t)(row0 + lr) * 256 + lc + 8];
  int4 b0v = *(const int4*)&Bm[(size_t)(col0 + lr) * 256 + lc];
  int4 b1v = *(const int4*)&Bm[(size_t)(col0 + lr) * 256 + lc + 8];

  for (int it = 0; it < 4; ++it) {
    __syncthreads();
    *(int4*)&As[lr * 72 + lc]     = a0v;
    *(int4*)&As[lr * 72 + lc + 8] = a1v;
    *(int4*)&Bs[lr * 72 + lc]     = b0v;
    *(int4*)&Bs[lr * 72 + lc + 8] = b1v;
    __syncthreads();

    if (it < 3) {
      const int k0 = (it + 1) << 6;
      a0v = *(const int4*)&A[(size_t)(row0 + lr) * 256 + k0 + lc];
      a1v = *(const int4*)&A[(size_t)(row0 + lr) * 256 + k0 + lc + 8];
      b0v = *(const int4*)&Bm[(size_t)(col0 + lr) * 256 + k0 + lc];
      b1v = *(const int4*)&Bm[(size_t)(col0 + lr) * 256 + k0 + lc + 8];
    }

#pragma unroll
    for (int ks = 0; ks < 2; ++ks) {
      s16x8 af[2], bf[2];
#pragma unroll
      for (int m = 0; m < 2; ++m)
        af[m] = *(const s16x8*)&As[(wm * 32 + m * 16 + fr) * 72 + ks * 32 + fg];
#pragma unroll
      for (int n = 0; n < 2; ++n)
        bf[n] = *(const s16x8*)&Bs[(wn * 32 + n * 16 + fr) * 72 + ks * 32 + fg];
#pragma unroll
      for (int m = 0; m < 2; ++m)
#pragma unroll
        for (int n = 0; n < 2; ++n)
          acc[m][n] = __builtin_amdgcn_mfma_f32_16x16x32_bf16(af[m], bf[n], acc[m][n], 0, 0, 0);
    }
  }

  const int fq = lane >> 4;
#pragma unroll
  for (int n = 0; n < 2; ++n) {
    const int col = col0 + wn * 32 + n * 16 + fr;
#pragma unroll
    for (int m = 0; m < 2; ++m) {
#pragma unroll
      for (int i = 0; i < 4; ++i) {
        const int row = row0 + wm * 32 + m * 16 + fq * 4 + i;
        ctxbf[(size_t)(b * 256 + row) * 512 + col] = f2bf(acc[m][n][i]);
      }
    }
  }
}

// ---------------------------------------------------------------------------
extern "C" void kernel_launch(void* const* d_in, const int* in_sizes, int n_in,
                              void* d_out, int out_size, void* d_ws, size_t ws_size,
                              hipStream_t stream) {
  const float* query = (const float*)d_in[0];
  const float* keys  = (const float*)d_in[1];
  const float* Wq    = (const float*)d_in[2];
  const float* bq    = (const float*)d_in[3];
  const float* w_att = (const float*)d_in[4];
  const float* b_att = (const float*)d_in[5];
  const float* Wout  = (const float*)d_in[6];
  const float* bout  = (const float*)d_in[7];

  float* out_tanh = (float*)d_out;                  // [4096][512]
  float* out_p    = out_tanh + (size_t)4096 * 512;  // [4096][256]

  float* ws = (float*)d_ws;
  float* Ea     = ws;                    // [4096][512] f32 (dead after K2)
  float* Ek     = ws + 2097152;          // [4096][512] f32 (dead after K2)
  float* S      = ws + 4194304;          // [4][4096][256] f32 (dead after K3a)
  float* Cptr   = ws + 8388608;          // [1] (+pad to 16)
  u16*   Wqt    = (u16*)(ws + 8388624);  // [512][512] bf16
  u16*   Woutt  = Wqt + 262144;          // [512][1024] bf16
  u16*   qbf    = Woutt + 524288;        // [4096][512] bf16
  u16*   kbfT   = qbf + 2097152;         // [16][512][256] bf16
  u16*   pbf    = kbfT + 2097152;        // [16][256][256] bf16
  u16*   ctxbf  = (u16*)Ea;              // [4096][512] bf16, aliases dead Ea

  // One fused prep launch: Ek, Cptr, qbf, kbfT, Wqt, Woutt
  mega_prep<<<5888, 256, 0, stream>>>(
      keys, Ek, query, qbf, kbfT, Wq, Wqt, Wout, Woutt, w_att, b_att, Cptr);

  // K1: Ea = exp2(C2 * (qbf @ Wq + bq))   [MFMA bf16, BK=64]
  gemm_mfma_bf16<<<dim3(8, 64), 256, 0, stream>>>(
      qbf, qbf, 512, Wqt, bq, Ea, 512, 2);

  // K2: partial scores (4 n-quarters), packed-fp32 inner math
  score_kernel<<<dim3(4, 4, 64), 256, 0, stream>>>(
      Ea, Ek, w_att, Cptr, S);

  // K3a: softmax (writes p fp32 + pbf bf16)
  softmax_kernel<<<1024, 256, 0, stream>>>(S, out_p, pbf);

  // K3b: ctxbf = pbf @ kbfT   [batched MFMA bf16]
  ctx_gemm<<<dim3(8, 4, 16), 256, 0, stream>>>(pbf, kbfT, ctxbf);

  // K4: out = tanh(concat(qbf, ctxbf) @ Wout + bout)   [MFMA bf16, BK=64]
  gemm_mfma_bf16<<<dim3(8, 64), 256, 0, stream>>>(
      qbf, ctxbf, 512, Woutt, bout, out_tanh, 1024, 1);
}